// Round 11
// baseline (1355.110 us; speedup 1.0000x reference)
//
#include <hip/hip_runtime.h>

constexpr int N_NODES = 100000;
constexpr int N_EDGES = 1600000;
constexpr int NBK  = 391;    // buckets of 256 nodes (node >> 8)
constexpr int NBLK = 640;    // partition blocks
constexpr int CHUNK = 2500;  // edges per block
constexpr int LCNT = NBK * NBLK;
constexpr int SCAN_BLKS = (LCNT + 255) / 256;
constexpr size_t NS3 = (size_t)N_NODES * 3;   // uint2 per 12-col slice

// ---------------- bf16 helpers (RNE) ----------------

__device__ __forceinline__ unsigned bf16pack(float a, float b) {
    unsigned ua = __float_as_uint(a), ub = __float_as_uint(b);
    ua += 0x7fffu + ((ua >> 16) & 1u);
    ub += 0x7fffu + ((ub >> 16) & 1u);
    return (ua >> 16) | (ub & 0xffff0000u);
}
__device__ __forceinline__ float bflo(unsigned p) { return __uint_as_float(p << 16); }
__device__ __forceinline__ float bfhi(unsigned p) { return __uint_as_float(p & 0xffff0000u); }

// ---------------- preprocessing (proven, unchanged) ----------------

__global__ __launch_bounds__(256) void part_count_kernel(
    const int* __restrict__ ei, int* __restrict__ cntD, int* __restrict__ cntS) {
    __shared__ int hd[NBK], hs[NBK];
    int tid = threadIdx.x;
    for (int i = tid; i < NBK; i += 256) { hd[i] = 0; hs[i] = 0; }
    __syncthreads();
    int e0 = blockIdx.x * CHUNK;
    for (int e = e0 + tid; e < e0 + CHUNK; e += 256) {
        int s = ei[e], d = ei[N_EDGES + e];
        atomicAdd(&hs[s >> 8], 1);
        atomicAdd(&hd[d >> 8], 1);
    }
    __syncthreads();
    for (int i = tid; i < NBK; i += 256) {
        cntD[i * NBLK + blockIdx.x] = hd[i];
        cntS[i * NBLK + blockIdx.x] = hs[i];
    }
}

__global__ __launch_bounds__(256) void scanA_kernel(const int* __restrict__ in,
                                                    int* __restrict__ out,
                                                    int* __restrict__ bsum, int L) {
    __shared__ int sm[256];
    int i = blockIdx.x * 256 + threadIdx.x;
    int v = (i < L) ? in[i] : 0;
    sm[threadIdx.x] = v;
    __syncthreads();
    for (int off = 1; off < 256; off <<= 1) {
        int t = (threadIdx.x >= off) ? sm[threadIdx.x - off] : 0;
        __syncthreads();
        sm[threadIdx.x] += t;
        __syncthreads();
    }
    if (i < L) out[i] = sm[threadIdx.x] - v;
    if (threadIdx.x == 255) bsum[blockIdx.x] = sm[255];
}

__global__ __launch_bounds__(1024) void scanB_kernel(int* __restrict__ bsum, int nb) {
    __shared__ int sm[1024];
    int t = threadIdx.x;
    int v = (t < nb) ? bsum[t] : 0;
    sm[t] = v;
    __syncthreads();
    for (int off = 1; off < 1024; off <<= 1) {
        int u = (t >= off) ? sm[t - off] : 0;
        __syncthreads();
        sm[t] += u;
        __syncthreads();
    }
    if (t < nb) bsum[t] = sm[t] - v;
}

__global__ __launch_bounds__(256) void scanC_kernel(int* __restrict__ out,
                                                    const int* __restrict__ bsum, int L) {
    int i = blockIdx.x * 256 + threadIdx.x;
    if (i < L) out[i] += bsum[blockIdx.x];
}

__global__ __launch_bounds__(256) void part_scatter_kernel(
    const int* __restrict__ ei, const int* __restrict__ scanD,
    const int* __restrict__ scanS, int2* __restrict__ edgepart,
    int* __restrict__ srcpart) {
    __shared__ int curD[NBK], curS[NBK];
    int tid = threadIdx.x;
    for (int i = tid; i < NBK; i += 256) {
        curD[i] = scanD[i * NBLK + blockIdx.x];
        curS[i] = scanS[i * NBLK + blockIdx.x];
    }
    __syncthreads();
    int e0 = blockIdx.x * CHUNK;
    for (int e = e0 + tid; e < e0 + CHUNK; e += 256) {
        int s = ei[e], d = ei[N_EDGES + e];
        int pd = atomicAdd(&curD[d >> 8], 1);
        edgepart[pd] = make_int2(s, d);
        int ps = atomicAdd(&curS[s >> 8], 1);
        srcpart[ps] = s;
    }
}

__global__ __launch_bounds__(256) void deg_kernel(const int* __restrict__ srcpart,
                                                  const int* __restrict__ scanS,
                                                  float* __restrict__ dis) {
    __shared__ int cnt[256];
    int b = blockIdx.x, tid = threadIdx.x;
    cnt[tid] = 0;
    __syncthreads();
    int beg = scanS[b * NBLK];
    int end = (b + 1 < NBK) ? scanS[(b + 1) * NBLK] : N_EDGES;
    for (int j = beg + tid; j < end; j += 256)
        atomicAdd(&cnt[srcpart[j] & 255], 1);
    __syncthreads();
    int node = b * 256 + tid;
    if (node < N_NODES) dis[node] = cnt[tid] > 0 ? rsqrtf((float)cnt[tid]) : 0.f;
}

__global__ __launch_bounds__(256) void csr_kernel(const int2* __restrict__ edgepart,
                                                  const int* __restrict__ scanD,
                                                  const float* __restrict__ dis,
                                                  int* __restrict__ rp,
                                                  int2* __restrict__ csrw) {
    __shared__ int cnt[256];
    __shared__ int lofs[256];
    __shared__ float disl[256];
    int b = blockIdx.x, tid = threadIdx.x;
    int beg = scanD[b * NBLK];
    int end = (b + 1 < NBK) ? scanD[(b + 1) * NBLK] : N_EDGES;
    int node = b * 256 + tid;
    cnt[tid] = 0;
    disl[tid] = (node < N_NODES) ? dis[node] : 0.f;
    __syncthreads();
    for (int j = beg + tid; j < end; j += 256)
        atomicAdd(&cnt[edgepart[j].y & 255], 1);
    __syncthreads();
    int v = cnt[tid];
    lofs[tid] = v;
    __syncthreads();
    for (int off = 1; off < 256; off <<= 1) {
        int t = (tid >= off) ? lofs[tid - off] : 0;
        __syncthreads();
        lofs[tid] += t;
        __syncthreads();
    }
    int myexc = lofs[tid] - v;
    if (node < N_NODES) rp[node] = beg + myexc;
    if (b == NBK - 1 && tid == 0) rp[N_NODES] = N_EDGES;
    __syncthreads();
    lofs[tid] = myexc;
    cnt[tid] = 0;
    __syncthreads();
    for (int j = beg + tid; j < end; j += 256) {
        int2 e = edgepart[j];
        int dl = e.y & 255;
        int pos = beg + lofs[dl] + atomicAdd(&cnt[dl], 1);
        csrw[pos] = make_int2(e.x, __float_as_int(-dis[e.x] * disl[dl]));
    }
}

// pack x [N,64] f32 -> bf16 row-major (16 uint2 = 128B rows)
__global__ void pack_x_kernel(const float* __restrict__ x, uint2* __restrict__ xbf) {
    int i = blockIdx.x * blockDim.x + threadIdx.x;
    if (i >= N_NODES * 16) return;
    float4 v = ((const float4*)x)[i];
    xbf[i] = make_uint2(bf16pack(v.x, v.y), bf16pack(v.z, v.w));
}

// ---------------- projection: Y = A'@W (36 cols), slice-major bf16 out --------
// A bf16: FI=64 -> row-major 128B rows (xbf); FI=36 -> slice-major [3][N][3]u2.

template <int FI, bool BN_A, bool BIAS_RELU, bool FUSE_STATS>
__global__ __launch_bounds__(256) void proj_kernel(
    const uint2* __restrict__ Ab, const float* __restrict__ W,
    const float* __restrict__ ss, const float* __restrict__ bias,
    uint2* __restrict__ Yout, float* __restrict__ partials) {
    constexpr int RU2 = FI / 4;
    __shared__ float Wl[FI * 36];
    __shared__ float Atile[28][FI + 1];
    __shared__ float ls[72];
    int tid = threadIdx.x;                       // 252 = 28 rows x 9 lanes
    for (int i = tid; i < FI * 36; i += 252) Wl[i] = W[i];
    int r0 = blockIdx.x * 28;
    const long long* ab8 = (const long long*)Ab;
    for (int i = tid; i < 28 * RU2; i += 252) {
        int r = i / RU2, u = i % RU2;
        int row = r0 + r;
        size_t idx;
        if (FI == 64) idx = (size_t)row * 16 + u;
        else          idx = (size_t)(u / 3) * NS3 + (size_t)row * 3 + (u % 3);
        long long av = (row < N_NODES) ? __builtin_nontemporal_load(ab8 + idx) : 0LL;
        unsigned lo = (unsigned)av, hi = (unsigned)(av >> 32);
        float f0 = bflo(lo), f1 = bfhi(lo), f2 = bflo(hi), f3 = bfhi(hi);
        if (BN_A) {
            int f = u * 4;
            f0 = fmaxf(fmaf(ss[f + 0], f0, ss[36 + f + 0]), 0.f);
            f1 = fmaxf(fmaf(ss[f + 1], f1, ss[36 + f + 1]), 0.f);
            f2 = fmaxf(fmaf(ss[f + 2], f2, ss[36 + f + 2]), 0.f);
            f3 = fmaxf(fmaf(ss[f + 3], f3, ss[36 + f + 3]), 0.f);
        }
        Atile[r][u * 4 + 0] = f0; Atile[r][u * 4 + 1] = f1;
        Atile[r][u * 4 + 2] = f2; Atile[r][u * 4 + 3] = f3;
    }
    if (FUSE_STATS && tid < 72) ls[tid] = 0.f;
    __syncthreads();
    int r = tid / 9, c = tid % 9;
    int row = r0 + r;
    float px = 0, py = 0, pz = 0, pw = 0;
    const float4* Wl4 = (const float4*)Wl;
#pragma unroll 4
    for (int f = 0; f < FI; ++f) {
        float a = Atile[r][f];
        float4 wv = Wl4[f * 9 + c];
        px = fmaf(a, wv.x, px); py = fmaf(a, wv.y, py);
        pz = fmaf(a, wv.z, pz); pw = fmaf(a, wv.w, pw);
    }
    if (BIAS_RELU) {
        px = fmaxf(px + bias[c * 4 + 0], 0.f);
        py = fmaxf(py + bias[c * 4 + 1], 0.f);
        pz = fmaxf(pz + bias[c * 4 + 2], 0.f);
        pw = fmaxf(pw + bias[c * 4 + 3], 0.f);
    }
    if (row < N_NODES) {
        unsigned long long pv = (unsigned long long)bf16pack(px, py)
                              | ((unsigned long long)bf16pack(pz, pw) << 32);
        __builtin_nontemporal_store(
            pv, (unsigned long long*)(Yout + (size_t)(c / 3) * NS3) + (size_t)row * 3 + (c % 3));
        if (FUSE_STATS) {
            atomicAdd(&ls[c * 4 + 0], px); atomicAdd(&ls[36 + c * 4 + 0], px * px);
            atomicAdd(&ls[c * 4 + 1], py); atomicAdd(&ls[36 + c * 4 + 1], py * py);
            atomicAdd(&ls[c * 4 + 2], pz); atomicAdd(&ls[36 + c * 4 + 2], pz * pz);
            atomicAdd(&ls[c * 4 + 3], pw); atomicAdd(&ls[36 + c * 4 + 3], pw * pw);
        }
    }
    if (FUSE_STATS) {
        __syncthreads();
        if (tid < 72) partials[(size_t)blockIdx.x * 72 + tid] = ls[tid];
    }
}

// ---------------- sliced gather step ----------------
// OUT_s[row] = SCALE * sum_j (w_j?) IN_s[src_j] + Y_s[row] (- B2_s[row]) (+bias,relu)
// Slice = 12 cols = 3 uint2 = 24B rows; buffer 2.4MB -> fits per-XCD L2.
// IN gathered with normal loads (hot); Y/B2 streamed once -> nt; OUT nt-stored.

template <int SCALE, bool WEIGHTED, bool HAS_B2, bool BIAS_RELU, bool FUSE_STATS>
__global__ __launch_bounds__(256) void gstep_kernel(
    const int* __restrict__ rp, const int2* __restrict__ csrw,
    const uint2* __restrict__ INs, const uint2* __restrict__ Ys,
    const uint2* __restrict__ B2s, const float* __restrict__ bias,
    uint2* __restrict__ OUTs, float* __restrict__ partials, int s) {
    __shared__ float ls[24];
    int tid = threadIdx.x;                       // 252 = 84 rows x 3 lanes
    if (FUSE_STATS) { if (tid < 24) ls[tid] = 0.f; __syncthreads(); }
    int r = tid / 3, c = tid % 3;
    int row = blockIdx.x * 84 + r;
    bool valid = row < N_NODES;
    float ox = 0, oy = 0, oz = 0, ow = 0;
    if (valid) {
        long long yv = __builtin_nontemporal_load((const long long*)Ys + (size_t)row * 3 + c);
        float ax = 0, ay = 0, az = 0, aw = 0;
        float bx = 0, by = 0, bz = 0, bw = 0;
        float cx = 0, cy = 0, cz = 0, cw = 0;
        float dx = 0, dy = 0, dz = 0, dw = 0;
        int beg = rp[row], end = rp[row + 1];
        int j = beg;
        for (; j + 7 < end; j += 8) {
            int2 e0 = csrw[j],     e1 = csrw[j + 1], e2 = csrw[j + 2], e3 = csrw[j + 3];
            int2 e4 = csrw[j + 4], e5 = csrw[j + 5], e6 = csrw[j + 6], e7 = csrw[j + 7];
            uint2 u0 = INs[(size_t)e0.x * 3 + c];
            uint2 u1 = INs[(size_t)e1.x * 3 + c];
            uint2 u2 = INs[(size_t)e2.x * 3 + c];
            uint2 u3 = INs[(size_t)e3.x * 3 + c];
            uint2 u4 = INs[(size_t)e4.x * 3 + c];
            uint2 u5 = INs[(size_t)e5.x * 3 + c];
            uint2 u6 = INs[(size_t)e6.x * 3 + c];
            uint2 u7 = INs[(size_t)e7.x * 3 + c];
            if (WEIGHTED) {
                float w0 = __int_as_float(e0.y), w1 = __int_as_float(e1.y);
                float w2 = __int_as_float(e2.y), w3 = __int_as_float(e3.y);
                float w4 = __int_as_float(e4.y), w5 = __int_as_float(e5.y);
                float w6 = __int_as_float(e6.y), w7 = __int_as_float(e7.y);
                ax = fmaf(w0, bflo(u0.x), ax); ay = fmaf(w0, bfhi(u0.x), ay);
                az = fmaf(w0, bflo(u0.y), az); aw = fmaf(w0, bfhi(u0.y), aw);
                bx = fmaf(w1, bflo(u1.x), bx); by = fmaf(w1, bfhi(u1.x), by);
                bz = fmaf(w1, bflo(u1.y), bz); bw = fmaf(w1, bfhi(u1.y), bw);
                cx = fmaf(w2, bflo(u2.x), cx); cy = fmaf(w2, bfhi(u2.x), cy);
                cz = fmaf(w2, bflo(u2.y), cz); cw = fmaf(w2, bfhi(u2.y), cw);
                dx = fmaf(w3, bflo(u3.x), dx); dy = fmaf(w3, bfhi(u3.x), dy);
                dz = fmaf(w3, bflo(u3.y), dz); dw = fmaf(w3, bfhi(u3.y), dw);
                ax = fmaf(w4, bflo(u4.x), ax); ay = fmaf(w4, bfhi(u4.x), ay);
                az = fmaf(w4, bflo(u4.y), az); aw = fmaf(w4, bfhi(u4.y), aw);
                bx = fmaf(w5, bflo(u5.x), bx); by = fmaf(w5, bfhi(u5.x), by);
                bz = fmaf(w5, bflo(u5.y), bz); bw = fmaf(w5, bfhi(u5.y), bw);
                cx = fmaf(w6, bflo(u6.x), cx); cy = fmaf(w6, bfhi(u6.x), cy);
                cz = fmaf(w6, bflo(u6.y), cz); cw = fmaf(w6, bfhi(u6.y), cw);
                dx = fmaf(w7, bflo(u7.x), dx); dy = fmaf(w7, bfhi(u7.x), dy);
                dz = fmaf(w7, bflo(u7.y), dz); dw = fmaf(w7, bfhi(u7.y), dw);
            } else {
                ax += bflo(u0.x) + bflo(u4.x); ay += bfhi(u0.x) + bfhi(u4.x);
                az += bflo(u0.y) + bflo(u4.y); aw += bfhi(u0.y) + bfhi(u4.y);
                bx += bflo(u1.x) + bflo(u5.x); by += bfhi(u1.x) + bfhi(u5.x);
                bz += bflo(u1.y) + bflo(u5.y); bw += bfhi(u1.y) + bfhi(u5.y);
                cx += bflo(u2.x) + bflo(u6.x); cy += bfhi(u2.x) + bfhi(u6.x);
                cz += bflo(u2.y) + bflo(u6.y); cw += bfhi(u2.y) + bfhi(u6.y);
                dx += bflo(u3.x) + bflo(u7.x); dy += bfhi(u3.x) + bfhi(u7.x);
                dz += bflo(u3.y) + bflo(u7.y); dw += bfhi(u3.y) + bfhi(u7.y);
            }
        }
        for (; j < end; ++j) {
            int2 e = csrw[j];
            uint2 u = INs[(size_t)e.x * 3 + c];
            if (WEIGHTED) {
                float w = __int_as_float(e.y);
                ax = fmaf(w, bflo(u.x), ax); ay = fmaf(w, bfhi(u.x), ay);
                az = fmaf(w, bflo(u.y), az); aw = fmaf(w, bfhi(u.y), aw);
            } else {
                ax += bflo(u.x); ay += bfhi(u.x);
                az += bflo(u.y); aw += bfhi(u.y);
            }
        }
        ax += bx + cx + dx; ay += by + cy + dy;
        az += bz + cz + dz; aw += bw + cw + dw;
        const float S = (float)SCALE;
        unsigned ylo = (unsigned)yv, yhi = (unsigned)(yv >> 32);
        ox = fmaf(S, ax, bflo(ylo)); oy = fmaf(S, ay, bfhi(ylo));
        oz = fmaf(S, az, bflo(yhi)); ow = fmaf(S, aw, bfhi(yhi));
        if (HAS_B2) {
            long long bv = __builtin_nontemporal_load((const long long*)B2s + (size_t)row * 3 + c);
            unsigned blo = (unsigned)bv, bhi = (unsigned)(bv >> 32);
            ox -= bflo(blo); oy -= bfhi(blo);
            oz -= bflo(bhi); ow -= bfhi(bhi);
        }
        if (BIAS_RELU) {
            int cb = s * 12 + c * 4;
            ox = fmaxf(ox + bias[cb + 0], 0.f); oy = fmaxf(oy + bias[cb + 1], 0.f);
            oz = fmaxf(oz + bias[cb + 2], 0.f); ow = fmaxf(ow + bias[cb + 3], 0.f);
        }
        unsigned long long pv = (unsigned long long)bf16pack(ox, oy)
                              | ((unsigned long long)bf16pack(oz, ow) << 32);
        __builtin_nontemporal_store(pv, (unsigned long long*)OUTs + (size_t)row * 3 + c);
        if (FUSE_STATS) {
            atomicAdd(&ls[c * 4 + 0], ox); atomicAdd(&ls[12 + c * 4 + 0], ox * ox);
            atomicAdd(&ls[c * 4 + 1], oy); atomicAdd(&ls[12 + c * 4 + 1], oy * oy);
            atomicAdd(&ls[c * 4 + 2], oz); atomicAdd(&ls[12 + c * 4 + 2], oz * oz);
            atomicAdd(&ls[c * 4 + 3], ow); atomicAdd(&ls[12 + c * 4 + 3], ow * ow);
        }
    }
    if (FUSE_STATS) {
        __syncthreads();
        if (tid < 12) {
            partials[(size_t)blockIdx.x * 72 + s * 12 + tid] = ls[tid];
            partials[(size_t)blockIdx.x * 72 + 36 + s * 12 + tid] = ls[12 + tid];
        }
    }
}

// ---------------- finalize: reduce partials -> BN scale/shift ----------------

__global__ __launch_bounds__(256) void finalize_kernel(
    const float* __restrict__ partials, int nb, const float* __restrict__ g,
    const float* __restrict__ be, float* __restrict__ ss) {
    __shared__ float rs[256], rq[256];
    int c = blockIdx.x;
    int t = threadIdx.x;
    float s = 0.f, q = 0.f;
    for (int i = t; i < nb; i += 256) {
        s += partials[(size_t)i * 72 + c];
        q += partials[(size_t)i * 72 + c + 36];
    }
    rs[t] = s; rq[t] = q;
    __syncthreads();
    for (int off = 128; off > 0; off >>= 1) {
        if (t < off) { rs[t] += rs[t + off]; rq[t] += rq[t + off]; }
        __syncthreads();
    }
    if (t == 0) {
        float m = rs[0] / (float)N_NODES;
        float v = rq[0] / (float)N_NODES - m * m;
        float sc = g[c] * rsqrtf(v + 1e-5f);
        ss[c] = sc;
        ss[36 + c] = be[c] - m * sc;
    }
}

// ---------------- final concat GEMM, bf16 slice-major inputs ----------------

__global__ __launch_bounds__(256) void fused3_kernel(
    const uint2* __restrict__ X1b, const float* __restrict__ ssA,
    const uint2* __restrict__ X2b, const float* __restrict__ ssB,
    const uint2* __restrict__ X3b, const float* __restrict__ ssC,
    const float* __restrict__ W, const float* __restrict__ b,
    float* __restrict__ out) {
    __shared__ float Wl[108 * 32];
    __shared__ float Al[32][109];
    int tid = threadIdx.x;
    for (int i = tid; i < 108 * 32; i += 256) Wl[i] = W[i];
    int r0 = blockIdx.x * 32;
    for (int i = tid; i < 32 * 108; i += 256) {
        int r = i / 108, f = i % 108;
        int row = r0 + r;
        float v = 0.f;
        if (row < N_NODES) {
            int t = f / 36, ff = f % 36, sl = ff / 12, w = ff % 12;
            const uint2* base = (t == 0 ? X1b : (t == 1 ? X2b : X3b)) + (size_t)sl * NS3;
            unsigned short u16 = ((const unsigned short*)base)[(size_t)row * 12 + w];
            float xv = __uint_as_float((unsigned)u16 << 16);
            if (t == 0)      v = fmaxf(fmaf(ssA[ff], xv, ssA[36 + ff]), 0.f);
            else if (t == 1) v = fmaxf(fmaf(ssB[ff], xv, ssB[36 + ff]), 0.f);
            else             v = fmaf(ssC[ff], xv, ssC[36 + ff]);
        }
        Al[r][f] = v;
    }
    __syncthreads();
    int r = tid >> 3, q = tid & 7;
    int row = r0 + r;
    if (row >= N_NODES) return;
    float acc[4];
#pragma unroll
    for (int j = 0; j < 4; ++j) acc[j] = b[q * 4 + j];
    for (int f = 0; f < 108; ++f) {
        float a = Al[r][f];
#pragma unroll
        for (int j = 0; j < 4; ++j)
            acc[j] = fmaf(a, Wl[f * 32 + q * 4 + j], acc[j]);
    }
#pragma unroll
    for (int j = 0; j < 4; ++j) out[(size_t)row * 32 + q * 4 + j] = acc[j];
}

// ---------------- launch ----------------

extern "C" void kernel_launch(void* const* d_in, const int* in_sizes, int n_in,
                              void* d_out, int out_size, void* d_ws, size_t ws_size,
                              hipStream_t stream) {
    const float* x      = (const float*)d_in[0];
    const int*   ei     = (const int*)d_in[1];
    const float* W1_1   = (const float*)d_in[2];
    // b1_1 / b1_2 cancel exactly under training-mode BN -> dropped.
    const float* g1_1   = (const float*)d_in[4];
    const float* be1_1  = (const float*)d_in[5];
    const float* W1_2   = (const float*)d_in[6];
    const float* g1_2   = (const float*)d_in[8];
    const float* be1_2  = (const float*)d_in[9];
    const float* gin_w1 = (const float*)d_in[10];
    const float* gin_b1 = (const float*)d_in[11];
    const float* gin_w2 = (const float*)d_in[12];
    const float* gin_b2 = (const float*)d_in[13];
    const float* g2     = (const float*)d_in[14];
    const float* be2    = (const float*)d_in[15];
    const float* W4     = (const float*)d_in[16];
    const float* b4     = (const float*)d_in[17];
    float* out = (float*)d_out;

    char* ws = (char*)d_ws;
    size_t off = 0;
    auto alloc = [&](size_t bytes) -> char* {
        char* p = ws + off;
        off = (off + bytes + 255) & ~(size_t)255;
        return p;
    };
    constexpr size_t SLICE_B = NS3 * 8;          // 2.4MB per slice
    constexpr size_t BUF36_B = SLICE_B * 3;      // 7.2MB full 36-col buffer
    int*   rp    = (int*)alloc((size_t)(N_NODES + 1) * 4);
    int2*  csrw  = (int2*)alloc((size_t)N_EDGES * 8);
    float* partials = (float*)alloc((size_t)4096 * 72 * 4);
    float* ssA   = (float*)alloc(72 * 4);
    float* ssB   = (float*)alloc(72 * 4);
    float* ssC   = (float*)alloc(72 * 4);
    uint2* xbf   = (uint2*)alloc((size_t)N_NODES * 128);
    // U region: preprocessing temporaries, later reused as Y[8] (57.6MB)
    char*  U     = alloc(8 * BUF36_B);
    uint2* R0    = (uint2*)alloc(BUF36_B);
    uint2* R1    = (uint2*)alloc(BUF36_B);
    uint2* R2    = (uint2*)alloc(BUF36_B);
    uint2* X1b   = (uint2*)alloc(BUF36_B);
    uint2* X2b   = (uint2*)alloc(BUF36_B);
    uint2* X3b   = (uint2*)alloc(BUF36_B);
    uint2* m1b   = (uint2*)alloc(BUF36_B);
    if (off > ws_size) return;

    // carve preprocessing temps from U (dead before Y is written)
    int*   cntD = (int*)U;
    int*   cntS = cntD + LCNT;
    int*   bsum = cntS + LCNT;
    float* dis  = (float*)(bsum + 1024);
    int2*  edgepart = (int2*)(dis + N_NODES);
    int*   srcpart  = (int*)(edgepart + N_EDGES);
    uint2* Yall = (uint2*)U;

    part_count_kernel<<<NBLK, 256, 0, stream>>>(ei, cntD, cntS);
    scanA_kernel<<<SCAN_BLKS, 256, 0, stream>>>(cntD, cntD, bsum, LCNT);
    scanB_kernel<<<1, 1024, 0, stream>>>(bsum, SCAN_BLKS);
    scanC_kernel<<<SCAN_BLKS, 256, 0, stream>>>(cntD, bsum, LCNT);
    scanA_kernel<<<SCAN_BLKS, 256, 0, stream>>>(cntS, cntS, bsum, LCNT);
    scanB_kernel<<<1, 1024, 0, stream>>>(bsum, SCAN_BLKS);
    scanC_kernel<<<SCAN_BLKS, 256, 0, stream>>>(cntS, bsum, LCNT);
    part_scatter_kernel<<<NBLK, 256, 0, stream>>>(ei, cntD, cntS, edgepart, srcpart);
    deg_kernel<<<NBK, 256, 0, stream>>>(srcpart, cntS, dis);
    csr_kernel<<<NBK, 256, 0, stream>>>(edgepart, cntD, dis, rp, csrw);
    pack_x_kernel<<<(N_NODES * 16 + 255) / 256, 256, 0, stream>>>(x, xbf);

    const int PBLKS = (N_NODES + 27) / 28;   // 3572
    const int GBLKS = (N_NODES + 83) / 84;   // 1191
    const int F3_BLKS = (N_NODES + 31) / 32; // 3125

    auto Y  = [&](int k) { return Yall + (size_t)k * (NS3 * 3); };
    auto SL = [&](uint2* base, int s) { return base + (size_t)s * NS3; };

    // ======== conv1_1: projections then 3 sliced Clenshaw chains ========
    for (int k = 7; k >= 0; --k)
        proj_kernel<64, false, false, false><<<PBLKS, 252, 0, stream>>>(
            xbf, W1_1 + k * 2304, nullptr, nullptr, Y(k), nullptr);
    for (int s = 0; s < 3; ++s) {
        gstep_kernel<2, true, false, false, false><<<GBLKS, 252, 0, stream>>>(
            rp, csrw, SL(Y(7), s), SL(Y(6), s), nullptr, nullptr, SL(R0, s), nullptr, s);
        gstep_kernel<2, true, true, false, false><<<GBLKS, 252, 0, stream>>>(
            rp, csrw, SL(R0, s), SL(Y(5), s), SL(Y(7), s), nullptr, SL(R1, s), nullptr, s);
        gstep_kernel<2, true, true, false, false><<<GBLKS, 252, 0, stream>>>(
            rp, csrw, SL(R1, s), SL(Y(4), s), SL(R0, s), nullptr, SL(R2, s), nullptr, s);
        gstep_kernel<2, true, true, false, false><<<GBLKS, 252, 0, stream>>>(
            rp, csrw, SL(R2, s), SL(Y(3), s), SL(R1, s), nullptr, SL(R0, s), nullptr, s);
        gstep_kernel<2, true, true, false, false><<<GBLKS, 252, 0, stream>>>(
            rp, csrw, SL(R0, s), SL(Y(2), s), SL(R2, s), nullptr, SL(R1, s), nullptr, s);
        gstep_kernel<2, true, true, false, false><<<GBLKS, 252, 0, stream>>>(
            rp, csrw, SL(R1, s), SL(Y(1), s), SL(R0, s), nullptr, SL(R2, s), nullptr, s);
        gstep_kernel<1, true, true, false, true><<<GBLKS, 252, 0, stream>>>(
            rp, csrw, SL(R2, s), SL(Y(0), s), SL(R1, s), nullptr, SL(X1b, s), partials, s);
    }
    finalize_kernel<<<36, 256, 0, stream>>>(partials, GBLKS, g1_1, be1_1, ssA);

    // ======== conv1_2: same with A = X1b (BN ssA applied in proj) ========
    for (int k = 7; k >= 0; --k)
        proj_kernel<36, true, false, false><<<PBLKS, 252, 0, stream>>>(
            X1b, W1_2 + k * 1296, ssA, nullptr, Y(k), nullptr);
    for (int s = 0; s < 3; ++s) {
        gstep_kernel<2, true, false, false, false><<<GBLKS, 252, 0, stream>>>(
            rp, csrw, SL(Y(7), s), SL(Y(6), s), nullptr, nullptr, SL(R0, s), nullptr, s);
        gstep_kernel<2, true, true, false, false><<<GBLKS, 252, 0, stream>>>(
            rp, csrw, SL(R0, s), SL(Y(5), s), SL(Y(7), s), nullptr, SL(R1, s), nullptr, s);
        gstep_kernel<2, true, true, false, false><<<GBLKS, 252, 0, stream>>>(
            rp, csrw, SL(R1, s), SL(Y(4), s), SL(R0, s), nullptr, SL(R2, s), nullptr, s);
        gstep_kernel<2, true, true, false, false><<<GBLKS, 252, 0, stream>>>(
            rp, csrw, SL(R2, s), SL(Y(3), s), SL(R1, s), nullptr, SL(R0, s), nullptr, s);
        gstep_kernel<2, true, true, false, false><<<GBLKS, 252, 0, stream>>>(
            rp, csrw, SL(R0, s), SL(Y(2), s), SL(R2, s), nullptr, SL(R1, s), nullptr, s);
        gstep_kernel<2, true, true, false, false><<<GBLKS, 252, 0, stream>>>(
            rp, csrw, SL(R1, s), SL(Y(1), s), SL(R0, s), nullptr, SL(R2, s), nullptr, s);
        gstep_kernel<1, true, true, false, true><<<GBLKS, 252, 0, stream>>>(
            rp, csrw, SL(R2, s), SL(Y(0), s), SL(R1, s), nullptr, SL(X2b, s), partials, s);
    }
    finalize_kernel<<<36, 256, 0, stream>>>(partials, GBLKS, g1_2, be1_2, ssB);

    // ======== GIN: y = x@w1; m1 = relu(y_self + sum y_src + b1); X3 = relu(m1@w2+b2) ====
    proj_kernel<64, false, false, false><<<PBLKS, 252, 0, stream>>>(
        xbf, gin_w1, nullptr, nullptr, Y(0), nullptr);
    for (int s = 0; s < 3; ++s)
        gstep_kernel<1, false, false, true, false><<<GBLKS, 252, 0, stream>>>(
            rp, csrw, SL(Y(0), s), SL(Y(0), s), nullptr, gin_b1, SL(m1b, s), nullptr, s);
    proj_kernel<36, false, true, true><<<PBLKS, 252, 0, stream>>>(
        m1b, gin_w2, nullptr, gin_b2, X3b, partials);
    finalize_kernel<<<36, 256, 0, stream>>>(partials, PBLKS, g2, be2, ssC);

    // ======== final concat GEMM ========
    fused3_kernel<<<F3_BLKS, 256, 0, stream>>>(X1b, ssA, X2b, ssB, X3b, ssC, W4, b4, out);
}

// Round 12
// 935.647 us; speedup vs baseline: 1.4483x; 1.4483x over previous
//
#include <hip/hip_runtime.h>

constexpr int N_NODES = 100000;
constexpr int N_EDGES = 1600000;
constexpr int NBK  = 391;    // buckets of 256 nodes (node >> 8)
constexpr int NBLK = 640;    // partition blocks
constexpr int CHUNK = 2500;  // edges per block: 640*2500 = 1.6M exactly
constexpr int LCNT = NBK * NBLK;            // 250240
constexpr int SCAN_BLKS = (LCNT + 255) / 256;  // 978

// ---------------- bf16 helpers (RNE) ----------------

__device__ __forceinline__ unsigned bf16pack(float a, float b) {
    unsigned ua = __float_as_uint(a), ub = __float_as_uint(b);
    ua += 0x7fffu + ((ua >> 16) & 1u);
    ub += 0x7fffu + ((ub >> 16) & 1u);
    return (ua >> 16) | (ub & 0xffff0000u);
}
__device__ __forceinline__ float bflo(unsigned p) { return __uint_as_float(p << 16); }
__device__ __forceinline__ float bfhi(unsigned p) { return __uint_as_float(p & 0xffff0000u); }

// packed edge: bits 0..16 = src (N<2^17); bits 17..31 = 15-bit weight
// (8 exp + 7 mant, sign implicit negative). Decode: 3 VALU ops.
__device__ __forceinline__ int esrc(unsigned v) { return (int)(v & 0x1FFFFu); }
__device__ __forceinline__ float ew(unsigned v) {
    return __uint_as_float(0x80000000u | ((v >> 17) << 16));
}

// ---------------- preprocessing: atomic-free two-level counting sort ----------

__global__ __launch_bounds__(256) void part_count_kernel(
    const int* __restrict__ ei, int* __restrict__ cntD, int* __restrict__ cntS) {
    __shared__ int hd[NBK], hs[NBK];
    int tid = threadIdx.x;
    for (int i = tid; i < NBK; i += 256) { hd[i] = 0; hs[i] = 0; }
    __syncthreads();
    int e0 = blockIdx.x * CHUNK;
    for (int e = e0 + tid; e < e0 + CHUNK; e += 256) {
        int s = ei[e], d = ei[N_EDGES + e];
        atomicAdd(&hs[s >> 8], 1);
        atomicAdd(&hd[d >> 8], 1);
    }
    __syncthreads();
    for (int i = tid; i < NBK; i += 256) {
        cntD[i * NBLK + blockIdx.x] = hd[i];
        cntS[i * NBLK + blockIdx.x] = hs[i];
    }
}

__global__ __launch_bounds__(256) void scanA_kernel(const int* __restrict__ in,
                                                    int* __restrict__ out,
                                                    int* __restrict__ bsum, int L) {
    __shared__ int sm[256];
    int i = blockIdx.x * 256 + threadIdx.x;
    int v = (i < L) ? in[i] : 0;
    sm[threadIdx.x] = v;
    __syncthreads();
    for (int off = 1; off < 256; off <<= 1) {
        int t = (threadIdx.x >= off) ? sm[threadIdx.x - off] : 0;
        __syncthreads();
        sm[threadIdx.x] += t;
        __syncthreads();
    }
    if (i < L) out[i] = sm[threadIdx.x] - v;
    if (threadIdx.x == 255) bsum[blockIdx.x] = sm[255];
}

__global__ __launch_bounds__(1024) void scanB_kernel(int* __restrict__ bsum, int nb) {
    __shared__ int sm[1024];
    int t = threadIdx.x;
    int v = (t < nb) ? bsum[t] : 0;
    sm[t] = v;
    __syncthreads();
    for (int off = 1; off < 1024; off <<= 1) {
        int u = (t >= off) ? sm[t - off] : 0;
        __syncthreads();
        sm[t] += u;
        __syncthreads();
    }
    if (t < nb) bsum[t] = sm[t] - v;
}

__global__ __launch_bounds__(256) void scanC_kernel(int* __restrict__ out,
                                                    const int* __restrict__ bsum, int L) {
    int i = blockIdx.x * 256 + threadIdx.x;
    if (i < L) out[i] += bsum[blockIdx.x];
}

__global__ __launch_bounds__(256) void part_scatter_kernel(
    const int* __restrict__ ei, const int* __restrict__ scanD,
    const int* __restrict__ scanS, int2* __restrict__ edgepart,
    int* __restrict__ srcpart) {
    __shared__ int curD[NBK], curS[NBK];
    int tid = threadIdx.x;
    for (int i = tid; i < NBK; i += 256) {
        curD[i] = scanD[i * NBLK + blockIdx.x];
        curS[i] = scanS[i * NBLK + blockIdx.x];
    }
    __syncthreads();
    int e0 = blockIdx.x * CHUNK;
    for (int e = e0 + tid; e < e0 + CHUNK; e += 256) {
        int s = ei[e], d = ei[N_EDGES + e];
        int pd = atomicAdd(&curD[d >> 8], 1);
        edgepart[pd] = make_int2(s, d);
        int ps = atomicAdd(&curS[s >> 8], 1);
        srcpart[ps] = s;
    }
}

__global__ __launch_bounds__(256) void deg_kernel(const int* __restrict__ srcpart,
                                                  const int* __restrict__ scanS,
                                                  float* __restrict__ dis) {
    __shared__ int cnt[256];
    int b = blockIdx.x, tid = threadIdx.x;
    cnt[tid] = 0;
    __syncthreads();
    int beg = scanS[b * NBLK];
    int end = (b + 1 < NBK) ? scanS[(b + 1) * NBLK] : N_EDGES;
    for (int j = beg + tid; j < end; j += 256)
        atomicAdd(&cnt[srcpart[j] & 255], 1);
    __syncthreads();
    int node = b * 256 + tid;
    if (node < N_NODES) dis[node] = cnt[tid] > 0 ? rsqrtf((float)cnt[tid]) : 0.f;
}

__global__ __launch_bounds__(256) void csr_kernel(const int2* __restrict__ edgepart,
                                                  const int* __restrict__ scanD,
                                                  const float* __restrict__ dis,
                                                  int* __restrict__ rp,
                                                  unsigned* __restrict__ csrc) {
    __shared__ int cnt[256];
    __shared__ int lofs[256];
    __shared__ float disl[256];
    int b = blockIdx.x, tid = threadIdx.x;
    int beg = scanD[b * NBLK];
    int end = (b + 1 < NBK) ? scanD[(b + 1) * NBLK] : N_EDGES;
    int node = b * 256 + tid;
    cnt[tid] = 0;
    disl[tid] = (node < N_NODES) ? dis[node] : 0.f;
    __syncthreads();
    for (int j = beg + tid; j < end; j += 256)
        atomicAdd(&cnt[edgepart[j].y & 255], 1);
    __syncthreads();
    int v = cnt[tid];
    lofs[tid] = v;
    __syncthreads();
    for (int off = 1; off < 256; off <<= 1) {
        int t = (tid >= off) ? lofs[tid - off] : 0;
        __syncthreads();
        lofs[tid] += t;
        __syncthreads();
    }
    int myexc = lofs[tid] - v;
    if (node < N_NODES) rp[node] = beg + myexc;
    if (b == NBK - 1 && tid == 0) rp[N_NODES] = N_EDGES;
    __syncthreads();
    lofs[tid] = myexc;
    cnt[tid] = 0;
    __syncthreads();
    for (int j = beg + tid; j < end; j += 256) {
        int2 e = edgepart[j];
        int dl = e.y & 255;
        int pos = beg + lofs[dl] + atomicAdd(&cnt[dl], 1);
        // pack: src | RNE-15bit(-dis[s]*dis[d]) << 17
        unsigned u = __float_as_uint(-(dis[e.x] * disl[dl]));
        u += 0x7fffu + ((u >> 16) & 1u);         // RNE to bf16 granularity
        unsigned wb = (u >> 16) & 0x7FFFu;       // drop sign (implicit negative)
        csrc[pos] = (unsigned)e.x | (wb << 17);
    }
}

// pack x [N,64] f32 -> bf16 (row = 16 uint2 = 128B)
__global__ void pack_x_kernel(const float* __restrict__ x, uint2* __restrict__ xbf) {
    int i = blockIdx.x * blockDim.x + threadIdx.x;     // over N*16
    if (i >= N_NODES * 16) return;
    float4 v = ((const float4*)x)[i];
    xbf[i] = make_uint2(bf16pack(v.x, v.y), bf16pack(v.z, v.w));
}

// ---------------- fused Clenshaw step ----------------
// OUT[row] = SCALE * sum_j w_j*INb[src_j] + A'[row]@W - (HAS_B2 ? B2b[row] : 0)
// INb/B2b bf16 packed rows (9 uint2 = 72B). Ab = bf16 A operand, nt-loaded.
// Edges: 4B packed (src|w15) via NORMAL cached loads (9-lane broadcast reuse).

template <int FI, int SCALE, bool HAS_B2, bool BN_A, bool FUSE_STATS, bool OUT_BF16, bool DUAL>
__global__ __launch_bounds__(256) void cheb_step_kernel(
    const int* __restrict__ rp, const unsigned* __restrict__ csrc,
    const uint2* __restrict__ INb, const uint2* __restrict__ B2b,
    const uint2* __restrict__ Ab, const float* __restrict__ W,
    const float* __restrict__ ss, void* __restrict__ OUT,
    unsigned long long* __restrict__ OUTB, float* __restrict__ partials) {
    constexpr int RU2 = FI / 4;                  // uint2 per A row
    __shared__ float Wl[FI * 36];
    __shared__ float Atile[28][FI + 1];
    __shared__ float ls[72];
    int tid = threadIdx.x;                       // 252 threads = 28 rows x 9 lanes
    for (int i = tid; i < FI * 36; i += 252) Wl[i] = W[i];
    int r0 = blockIdx.x * 28;
    const long long* ab8 = (const long long*)Ab;
    for (int i = tid; i < 28 * RU2; i += 252) {
        int r = i / RU2, u = i % RU2;
        int row = r0 + r;
        long long av = (row < N_NODES)
            ? __builtin_nontemporal_load(ab8 + (size_t)row * RU2 + u) : 0LL;
        unsigned lo = (unsigned)av, hi = (unsigned)(av >> 32);
        float f0 = bflo(lo), f1 = bfhi(lo), f2 = bflo(hi), f3 = bfhi(hi);
        if (BN_A) {
            int f = u * 4;
            f0 = fmaxf(fmaf(ss[f + 0], f0, ss[36 + f + 0]), 0.f);
            f1 = fmaxf(fmaf(ss[f + 1], f1, ss[36 + f + 1]), 0.f);
            f2 = fmaxf(fmaf(ss[f + 2], f2, ss[36 + f + 2]), 0.f);
            f3 = fmaxf(fmaf(ss[f + 3], f3, ss[36 + f + 3]), 0.f);
        }
        Atile[r][u * 4 + 0] = f0; Atile[r][u * 4 + 1] = f1;
        Atile[r][u * 4 + 2] = f2; Atile[r][u * 4 + 3] = f3;
    }
    if (FUSE_STATS && tid < 72) ls[tid] = 0.f;
    __syncthreads();
    int r = tid / 9, c = tid % 9;
    int row = r0 + r;
    bool valid = row < N_NODES;
    float ax = 0, ay = 0, az = 0, aw = 0;
    float bx = 0, by = 0, bz = 0, bw = 0;
    float cx = 0, cy = 0, cz = 0, cw = 0;
    float dx = 0, dy = 0, dz = 0, dw = 0;
    if (SCALE != 0 && valid) {
        int beg = rp[row], end = rp[row + 1];
        int j = beg;
        for (; j + 7 < end; j += 8) {
            unsigned v0 = csrc[j],     v1 = csrc[j + 1], v2 = csrc[j + 2], v3 = csrc[j + 3];
            unsigned v4 = csrc[j + 4], v5 = csrc[j + 5], v6 = csrc[j + 6], v7 = csrc[j + 7];
            uint2 u0 = INb[(size_t)esrc(v0) * 9 + c];
            uint2 u1 = INb[(size_t)esrc(v1) * 9 + c];
            uint2 u2 = INb[(size_t)esrc(v2) * 9 + c];
            uint2 u3 = INb[(size_t)esrc(v3) * 9 + c];
            uint2 u4 = INb[(size_t)esrc(v4) * 9 + c];
            uint2 u5 = INb[(size_t)esrc(v5) * 9 + c];
            uint2 u6 = INb[(size_t)esrc(v6) * 9 + c];
            uint2 u7 = INb[(size_t)esrc(v7) * 9 + c];
            float w0 = ew(v0), w1 = ew(v1), w2 = ew(v2), w3 = ew(v3);
            float w4 = ew(v4), w5 = ew(v5), w6 = ew(v6), w7 = ew(v7);
            ax = fmaf(w0, bflo(u0.x), ax); ay = fmaf(w0, bfhi(u0.x), ay);
            az = fmaf(w0, bflo(u0.y), az); aw = fmaf(w0, bfhi(u0.y), aw);
            bx = fmaf(w1, bflo(u1.x), bx); by = fmaf(w1, bfhi(u1.x), by);
            bz = fmaf(w1, bflo(u1.y), bz); bw = fmaf(w1, bfhi(u1.y), bw);
            cx = fmaf(w2, bflo(u2.x), cx); cy = fmaf(w2, bfhi(u2.x), cy);
            cz = fmaf(w2, bflo(u2.y), cz); cw = fmaf(w2, bfhi(u2.y), cw);
            dx = fmaf(w3, bflo(u3.x), dx); dy = fmaf(w3, bfhi(u3.x), dy);
            dz = fmaf(w3, bflo(u3.y), dz); dw = fmaf(w3, bfhi(u3.y), dw);
            ax = fmaf(w4, bflo(u4.x), ax); ay = fmaf(w4, bfhi(u4.x), ay);
            az = fmaf(w4, bflo(u4.y), az); aw = fmaf(w4, bfhi(u4.y), aw);
            bx = fmaf(w5, bflo(u5.x), bx); by = fmaf(w5, bfhi(u5.x), by);
            bz = fmaf(w5, bflo(u5.y), bz); bw = fmaf(w5, bfhi(u5.y), bw);
            cx = fmaf(w6, bflo(u6.x), cx); cy = fmaf(w6, bfhi(u6.x), cy);
            cz = fmaf(w6, bflo(u6.y), cz); cw = fmaf(w6, bfhi(u6.y), cw);
            dx = fmaf(w7, bflo(u7.x), dx); dy = fmaf(w7, bfhi(u7.x), dy);
            dz = fmaf(w7, bflo(u7.y), dz); dw = fmaf(w7, bfhi(u7.y), dw);
        }
        for (; j < end; ++j) {
            unsigned v = csrc[j];
            uint2 u = INb[(size_t)esrc(v) * 9 + c];
            float w = ew(v);
            ax = fmaf(w, bflo(u.x), ax); ay = fmaf(w, bfhi(u.x), ay);
            az = fmaf(w, bflo(u.y), az); aw = fmaf(w, bfhi(u.y), aw);
        }
        ax += bx + cx + dx; ay += by + cy + dy;
        az += bz + cz + dz; aw += bw + cw + dw;
    }
    float px = 0, py = 0, pz = 0, pw = 0;
    const float4* Wl4 = (const float4*)Wl;
#pragma unroll 4
    for (int f = 0; f < FI; ++f) {
        float a = Atile[r][f];
        float4 wv = Wl4[f * 9 + c];
        px = fmaf(a, wv.x, px); py = fmaf(a, wv.y, py);
        pz = fmaf(a, wv.z, pz); pw = fmaf(a, wv.w, pw);
    }
    const float S = (float)SCALE;
    float4 o;
    o.x = fmaf(S, ax, px); o.y = fmaf(S, ay, py);
    o.z = fmaf(S, az, pz); o.w = fmaf(S, aw, pw);
    if (valid) {
        if (HAS_B2) {
            uint2 u = B2b[(size_t)row * 9 + c];
            o.x -= bflo(u.x); o.y -= bfhi(u.x);
            o.z -= bflo(u.y); o.w -= bfhi(u.y);
        }
        if (OUT_BF16) {
            unsigned long long pv = (unsigned long long)bf16pack(o.x, o.y)
                                  | ((unsigned long long)bf16pack(o.z, o.w) << 32);
            __builtin_nontemporal_store(pv, (unsigned long long*)OUT + (size_t)row * 9 + c);
        } else {
            ((float4*)OUT)[(size_t)row * 9 + c] = o;
        }
        if (DUAL) {
            unsigned long long pv = (unsigned long long)bf16pack(o.x, o.y)
                                  | ((unsigned long long)bf16pack(o.z, o.w) << 32);
            __builtin_nontemporal_store(pv, OUTB + (size_t)row * 9 + c);
        }
        if (FUSE_STATS) {
            atomicAdd(&ls[c * 4 + 0], o.x); atomicAdd(&ls[36 + c * 4 + 0], o.x * o.x);
            atomicAdd(&ls[c * 4 + 1], o.y); atomicAdd(&ls[36 + c * 4 + 1], o.y * o.y);
            atomicAdd(&ls[c * 4 + 2], o.z); atomicAdd(&ls[36 + c * 4 + 2], o.z * o.z);
            atomicAdd(&ls[c * 4 + 3], o.w); atomicAdd(&ls[36 + c * 4 + 3], o.w * o.w);
        }
    }
    if (FUSE_STATS) {
        __syncthreads();
        if (tid < 72) partials[blockIdx.x * 72 + tid] = ls[tid];
    }
}

// ---------------- GIN gather (projection-first) ----------------

__global__ __launch_bounds__(256) void gin_gather_kernel(
    const int* __restrict__ rp, const unsigned* __restrict__ csrc,
    const uint2* __restrict__ Yb, const float* __restrict__ b1,
    const float* __restrict__ w2, const float* __restrict__ b2,
    float* __restrict__ OUT, float* __restrict__ partials) {
    __shared__ float W2l[36 * 36];
    __shared__ float B1l[36], B2l[36];
    __shared__ float M1t[28][37];
    __shared__ float ls[72];
    int tid = threadIdx.x;                       // 252 = 28 rows x 9 lanes
    for (int i = tid; i < 36 * 36; i += 252) W2l[i] = w2[i];
    if (tid < 36) { B1l[tid] = b1[tid]; B2l[tid] = b2[tid]; }
    if (tid < 72) ls[tid] = 0.f;
    __syncthreads();
    int r = tid / 9, c = tid % 9;
    int row = blockIdx.x * 28 + r;
    bool valid = row < N_NODES;
    float ax = 0, ay = 0, az = 0, aw = 0;
    float bx = 0, by = 0, bz = 0, bw = 0;
    float cx = 0, cy = 0, cz = 0, cw = 0;
    float dx = 0, dy = 0, dz = 0, dw = 0;
    if (valid) {
        uint2 us = Yb[(size_t)row * 9 + c];
        ax = bflo(us.x); ay = bfhi(us.x); az = bflo(us.y); aw = bfhi(us.y);
        int beg = rp[row], end = rp[row + 1];
        int j = beg;
        for (; j + 7 < end; j += 8) {
            int s0 = esrc(csrc[j]),     s1 = esrc(csrc[j + 1]);
            int s2 = esrc(csrc[j + 2]), s3 = esrc(csrc[j + 3]);
            int s4 = esrc(csrc[j + 4]), s5 = esrc(csrc[j + 5]);
            int s6 = esrc(csrc[j + 6]), s7 = esrc(csrc[j + 7]);
            uint2 u0 = Yb[(size_t)s0 * 9 + c];
            uint2 u1 = Yb[(size_t)s1 * 9 + c];
            uint2 u2 = Yb[(size_t)s2 * 9 + c];
            uint2 u3 = Yb[(size_t)s3 * 9 + c];
            uint2 u4 = Yb[(size_t)s4 * 9 + c];
            uint2 u5 = Yb[(size_t)s5 * 9 + c];
            uint2 u6 = Yb[(size_t)s6 * 9 + c];
            uint2 u7 = Yb[(size_t)s7 * 9 + c];
            ax += bflo(u0.x) + bflo(u4.x); ay += bfhi(u0.x) + bfhi(u4.x);
            az += bflo(u0.y) + bflo(u4.y); aw += bfhi(u0.y) + bfhi(u4.y);
            bx += bflo(u1.x) + bflo(u5.x); by += bfhi(u1.x) + bfhi(u5.x);
            bz += bflo(u1.y) + bflo(u5.y); bw += bfhi(u1.y) + bfhi(u5.y);
            cx += bflo(u2.x) + bflo(u6.x); cy += bfhi(u2.x) + bfhi(u6.x);
            cz += bflo(u2.y) + bflo(u6.y); cw += bfhi(u2.y) + bfhi(u6.y);
            dx += bflo(u3.x) + bflo(u7.x); dy += bfhi(u3.x) + bfhi(u7.x);
            dz += bflo(u3.y) + bflo(u7.y); dw += bfhi(u3.y) + bfhi(u7.y);
        }
        for (; j < end; ++j) {
            uint2 u = Yb[(size_t)esrc(csrc[j]) * 9 + c];
            ax += bflo(u.x); ay += bfhi(u.x);
            az += bflo(u.y); aw += bfhi(u.y);
        }
        ax += bx + cx + dx; ay += by + cy + dy;
        az += bz + cz + dz; aw += bw + cw + dw;
    }
    float m0 = fmaxf(ax + B1l[c * 4 + 0], 0.f);
    float m1 = fmaxf(ay + B1l[c * 4 + 1], 0.f);
    float m2 = fmaxf(az + B1l[c * 4 + 2], 0.f);
    float m3 = fmaxf(aw + B1l[c * 4 + 3], 0.f);
    M1t[r][c * 4 + 0] = m0; M1t[r][c * 4 + 1] = m1;
    M1t[r][c * 4 + 2] = m2; M1t[r][c * 4 + 3] = m3;
    __syncthreads();
    float o0 = B2l[c * 4 + 0], o1 = B2l[c * 4 + 1];
    float o2 = B2l[c * 4 + 2], o3 = B2l[c * 4 + 3];
    const float4* W2l4 = (const float4*)W2l;
#pragma unroll 4
    for (int f = 0; f < 36; ++f) {
        float a = M1t[r][f];
        float4 wv = W2l4[f * 9 + c];
        o0 = fmaf(a, wv.x, o0); o1 = fmaf(a, wv.y, o1);
        o2 = fmaf(a, wv.z, o2); o3 = fmaf(a, wv.w, o3);
    }
    o0 = fmaxf(o0, 0.f); o1 = fmaxf(o1, 0.f);
    o2 = fmaxf(o2, 0.f); o3 = fmaxf(o3, 0.f);
    if (valid) {
        float4 o = {o0, o1, o2, o3};
        ((float4*)OUT)[(size_t)row * 9 + c] = o;
        atomicAdd(&ls[c * 4 + 0], o0); atomicAdd(&ls[36 + c * 4 + 0], o0 * o0);
        atomicAdd(&ls[c * 4 + 1], o1); atomicAdd(&ls[36 + c * 4 + 1], o1 * o1);
        atomicAdd(&ls[c * 4 + 2], o2); atomicAdd(&ls[36 + c * 4 + 2], o2 * o2);
        atomicAdd(&ls[c * 4 + 3], o3); atomicAdd(&ls[36 + c * 4 + 3], o3 * o3);
    }
    __syncthreads();
    if (tid < 72) partials[blockIdx.x * 72 + tid] = ls[tid];
}

// ---------------- finalize: reduce partials -> BN scale/shift ----------------

__global__ __launch_bounds__(256) void finalize_kernel(
    const float* __restrict__ partials, int nb, const float* __restrict__ g,
    const float* __restrict__ be, float* __restrict__ ss) {
    __shared__ float rs[256], rq[256];
    int c = blockIdx.x;
    int t = threadIdx.x;
    float s = 0.f, q = 0.f;
    for (int i = t; i < nb; i += 256) {
        s += partials[i * 72 + c];
        q += partials[i * 72 + c + 36];
    }
    rs[t] = s; rq[t] = q;
    __syncthreads();
    for (int off = 128; off > 0; off >>= 1) {
        if (t < off) { rs[t] += rs[t + off]; rq[t] += rq[t + off]; }
        __syncthreads();
    }
    if (t == 0) {
        float m = rs[0] / (float)N_NODES;
        float v = rq[0] / (float)N_NODES - m * m;
        float sc = g[c] * rsqrtf(v + 1e-5f);
        ss[c] = sc;
        ss[36 + c] = be[c] - m * sc;
    }
}

// ---------------- final concat GEMM with BN folds (32 rows/block) ----------------

__global__ __launch_bounds__(256) void fused3_kernel(
    const float* __restrict__ X1, const float* __restrict__ ssA,
    const float* __restrict__ X2, const float* __restrict__ ssB,
    const float* __restrict__ X3, const float* __restrict__ ssC,
    const float* __restrict__ W, const float* __restrict__ b,
    float* __restrict__ out) {
    __shared__ float Wl[108 * 32];       // 13.8 KB
    __shared__ float Al[32][109];        // 13.9 KB
    int tid = threadIdx.x;
    for (int i = tid; i < 108 * 32; i += 256) Wl[i] = W[i];
    int r0 = blockIdx.x * 32;
    for (int i = tid; i < 32 * 108; i += 256) {
        int r = i / 108, f = i % 108;
        int row = r0 + r;
        float v = 0.f;
        if (row < N_NODES) {
            if (f < 36) {
                v = fmaxf(fmaf(ssA[f], X1[(size_t)row * 36 + f], ssA[36 + f]), 0.f);
            } else if (f < 72) {
                int ff = f - 36;
                v = fmaxf(fmaf(ssB[ff], X2[(size_t)row * 36 + ff], ssB[36 + ff]), 0.f);
            } else {
                int ff = f - 72;
                v = fmaf(ssC[ff], X3[(size_t)row * 36 + ff], ssC[36 + ff]);
            }
        }
        Al[r][f] = v;
    }
    __syncthreads();
    int r = tid >> 3, q = tid & 7;       // 32 rows x 8 threads, 4 cols each
    int row = r0 + r;
    if (row >= N_NODES) return;
    float acc[4];
#pragma unroll
    for (int j = 0; j < 4; ++j) acc[j] = b[q * 4 + j];
    for (int f = 0; f < 108; ++f) {
        float a = Al[r][f];
#pragma unroll
        for (int j = 0; j < 4; ++j)
            acc[j] = fmaf(a, Wl[f * 32 + q * 4 + j], acc[j]);
    }
#pragma unroll
    for (int j = 0; j < 4; ++j) out[(size_t)row * 32 + q * 4 + j] = acc[j];
}

// ---------------- launch ----------------

extern "C" void kernel_launch(void* const* d_in, const int* in_sizes, int n_in,
                              void* d_out, int out_size, void* d_ws, size_t ws_size,
                              hipStream_t stream) {
    const float* x      = (const float*)d_in[0];
    const int*   ei     = (const int*)d_in[1];
    const float* W1_1   = (const float*)d_in[2];
    // b1_1 / b1_2 cancel exactly under training-mode BN -> dropped.
    const float* g1_1   = (const float*)d_in[4];
    const float* be1_1  = (const float*)d_in[5];
    const float* W1_2   = (const float*)d_in[6];
    const float* g1_2   = (const float*)d_in[8];
    const float* be1_2  = (const float*)d_in[9];
    const float* gin_w1 = (const float*)d_in[10];
    const float* gin_b1 = (const float*)d_in[11];
    const float* gin_w2 = (const float*)d_in[12];
    const float* gin_b2 = (const float*)d_in[13];
    const float* g2     = (const float*)d_in[14];
    const float* be2    = (const float*)d_in[15];
    const float* W4     = (const float*)d_in[16];
    const float* b4     = (const float*)d_in[17];
    float* out = (float*)d_out;

    char* ws = (char*)d_ws;
    size_t off = 0;
    auto alloc = [&](size_t bytes) -> char* {
        char* p = ws + off;
        off = (off + bytes + 255) & ~(size_t)255;
        return p;
    };
    int*   cntD  = (int*)alloc((size_t)LCNT * 4);
    int*   cntS  = (int*)alloc((size_t)LCNT * 4);
    int*   bsum  = (int*)alloc(1024 * 4);
    int*   rp    = (int*)alloc((size_t)(N_NODES + 1) * 4);
    float* dis   = (float*)alloc((size_t)N_NODES * 4);
    int2*  edgepart = (int2*)alloc((size_t)N_EDGES * 8);
    int*   srcpart  = (int*)alloc((size_t)N_EDGES * 4);
    unsigned* csrc = (unsigned*)alloc((size_t)N_EDGES * 4);
    float* ssA   = (float*)alloc(72 * 4);
    float* ssB   = (float*)alloc(72 * 4);
    float* ssC   = (float*)alloc(72 * 4);
    float* partials = (float*)alloc((size_t)6250 * 72 * 4);
    constexpr size_t NB36 = (size_t)N_NODES * 36 * 4;      // f32 [N,36]
    constexpr size_t NBBF = (size_t)N_NODES * 72;          // bf16 packed 72B rows
    uint2* xbf = (uint2*)alloc((size_t)N_NODES * 128);     // bf16 [N,64] 128B rows
    uint2* R0  = (uint2*)alloc(NBBF);
    uint2* R1  = (uint2*)alloc(NBBF);
    uint2* R2  = (uint2*)alloc(NBBF);
    uint2* X1b = (uint2*)alloc(NBBF);
    float* X1  = (float*)alloc(NB36);
    float* X2  = (float*)alloc(NB36);
    float* X3  = (float*)alloc(NB36);
    if (off > ws_size) return;

    // ---- preprocessing: counting-sort CSR build (no global atomics) ----
    part_count_kernel<<<NBLK, 256, 0, stream>>>(ei, cntD, cntS);
    scanA_kernel<<<SCAN_BLKS, 256, 0, stream>>>(cntD, cntD, bsum, LCNT);
    scanB_kernel<<<1, 1024, 0, stream>>>(bsum, SCAN_BLKS);
    scanC_kernel<<<SCAN_BLKS, 256, 0, stream>>>(cntD, bsum, LCNT);
    scanA_kernel<<<SCAN_BLKS, 256, 0, stream>>>(cntS, cntS, bsum, LCNT);
    scanB_kernel<<<1, 1024, 0, stream>>>(bsum, SCAN_BLKS);
    scanC_kernel<<<SCAN_BLKS, 256, 0, stream>>>(cntS, bsum, LCNT);
    part_scatter_kernel<<<NBLK, 256, 0, stream>>>(ei, cntD, cntS, edgepart, srcpart);
    deg_kernel<<<NBK, 256, 0, stream>>>(srcpart, cntS, dis);
    csr_kernel<<<NBK, 256, 0, stream>>>(edgepart, cntD, dis, rp, csrc);
    pack_x_kernel<<<(N_NODES * 16 + 255) / 256, 256, 0, stream>>>(x, xbf);

    const int STEP_BLKS = (N_NODES + 27) / 28;        // 3572
    const int F3_BLKS   = (N_NODES + 31) / 32;        // 3125

    // ---- conv1_1 (Clenshaw, FI=64, A=xbf) ----
    cheb_step_kernel<64, 0, false, false, false, true, false><<<STEP_BLKS, 252, 0, stream>>>(
        rp, csrc, nullptr, nullptr, xbf, W1_1 + 7 * 2304, nullptr, R0, nullptr, nullptr);
    cheb_step_kernel<64, 2, false, false, false, true, false><<<STEP_BLKS, 252, 0, stream>>>(
        rp, csrc, R0, nullptr, xbf, W1_1 + 6 * 2304, nullptr, R1, nullptr, nullptr);
    cheb_step_kernel<64, 2, true, false, false, true, false><<<STEP_BLKS, 252, 0, stream>>>(
        rp, csrc, R1, R0, xbf, W1_1 + 5 * 2304, nullptr, R2, nullptr, nullptr);
    cheb_step_kernel<64, 2, true, false, false, true, false><<<STEP_BLKS, 252, 0, stream>>>(
        rp, csrc, R2, R1, xbf, W1_1 + 4 * 2304, nullptr, R0, nullptr, nullptr);
    cheb_step_kernel<64, 2, true, false, false, true, false><<<STEP_BLKS, 252, 0, stream>>>(
        rp, csrc, R0, R2, xbf, W1_1 + 3 * 2304, nullptr, R1, nullptr, nullptr);
    cheb_step_kernel<64, 2, true, false, false, true, false><<<STEP_BLKS, 252, 0, stream>>>(
        rp, csrc, R1, R0, xbf, W1_1 + 2 * 2304, nullptr, R2, nullptr, nullptr);
    cheb_step_kernel<64, 2, true, false, false, true, false><<<STEP_BLKS, 252, 0, stream>>>(
        rp, csrc, R2, R1, xbf, W1_1 + 1 * 2304, nullptr, R0, nullptr, nullptr);
    cheb_step_kernel<64, 1, true, false, true, false, true><<<STEP_BLKS, 252, 0, stream>>>(
        rp, csrc, R0, R2, xbf, W1_1 + 0 * 2304, nullptr, X1,
        (unsigned long long*)X1b, partials);
    finalize_kernel<<<36, 256, 0, stream>>>(partials, STEP_BLKS, g1_1, be1_1, ssA);

    // ---- conv1_2 (Clenshaw, FI=36, A=X1b with BN ssA) ----
    cheb_step_kernel<36, 0, false, true, false, true, false><<<STEP_BLKS, 252, 0, stream>>>(
        rp, csrc, nullptr, nullptr, X1b, W1_2 + 7 * 1296, ssA, R0, nullptr, nullptr);
    cheb_step_kernel<36, 2, false, true, false, true, false><<<STEP_BLKS, 252, 0, stream>>>(
        rp, csrc, R0, nullptr, X1b, W1_2 + 6 * 1296, ssA, R1, nullptr, nullptr);
    cheb_step_kernel<36, 2, true, true, false, true, false><<<STEP_BLKS, 252, 0, stream>>>(
        rp, csrc, R1, R0, X1b, W1_2 + 5 * 1296, ssA, R2, nullptr, nullptr);
    cheb_step_kernel<36, 2, true, true, false, true, false><<<STEP_BLKS, 252, 0, stream>>>(
        rp, csrc, R2, R1, X1b, W1_2 + 4 * 1296, ssA, R0, nullptr, nullptr);
    cheb_step_kernel<36, 2, true, true, false, true, false><<<STEP_BLKS, 252, 0, stream>>>(
        rp, csrc, R0, R2, X1b, W1_2 + 3 * 1296, ssA, R1, nullptr, nullptr);
    cheb_step_kernel<36, 2, true, true, false, true, false><<<STEP_BLKS, 252, 0, stream>>>(
        rp, csrc, R1, R0, X1b, W1_2 + 2 * 1296, ssA, R2, nullptr, nullptr);
    cheb_step_kernel<36, 2, true, true, false, true, false><<<STEP_BLKS, 252, 0, stream>>>(
        rp, csrc, R2, R1, X1b, W1_2 + 1 * 1296, ssA, R0, nullptr, nullptr);
    cheb_step_kernel<36, 1, true, true, true, false, false><<<STEP_BLKS, 252, 0, stream>>>(
        rp, csrc, R0, R2, X1b, W1_2 + 0 * 1296, ssA, X2, nullptr, partials);
    finalize_kernel<<<36, 256, 0, stream>>>(partials, STEP_BLKS, g1_2, be1_2, ssB);

    // ---- GIN (projection-first: y = x@gin_w1 from xbf, then 36-wide gather) ----
    cheb_step_kernel<64, 0, false, false, false, true, false><<<STEP_BLKS, 252, 0, stream>>>(
        rp, csrc, nullptr, nullptr, xbf, gin_w1, nullptr, R0, nullptr, nullptr);
    gin_gather_kernel<<<STEP_BLKS, 252, 0, stream>>>(rp, csrc, R0, gin_b1,
                                                     gin_w2, gin_b2, X3, partials);
    finalize_kernel<<<36, 256, 0, stream>>>(partials, STEP_BLKS, g2, be2, ssC);

    // ---- final concat GEMM ----
    fused3_kernel<<<F3_BLKS, 256, 0, stream>>>(X1, ssA, X2, ssB, X3, ssC, W4, b4, out);
}

// Round 13
// 920.000 us; speedup vs baseline: 1.4729x; 1.0170x over previous
//
#include <hip/hip_runtime.h>

constexpr int N_NODES = 100000;
constexpr int N_EDGES = 1600000;
constexpr int NBK  = 391;    // buckets of 256 nodes (node >> 8)
constexpr int NBLK = 640;    // partition blocks
constexpr int CHUNK = 2500;  // edges per block: 640*2500 = 1.6M exactly
constexpr int LCNT = NBK * NBLK;            // 250240
constexpr int SCAN_BLKS = (LCNT + 255) / 256;  // 978

// ---------------- bf16 helpers (RNE) ----------------

__device__ __forceinline__ unsigned bf16pack(float a, float b) {
    unsigned ua = __float_as_uint(a), ub = __float_as_uint(b);
    ua += 0x7fffu + ((ua >> 16) & 1u);
    ub += 0x7fffu + ((ub >> 16) & 1u);
    return (ua >> 16) | (ub & 0xffff0000u);
}
__device__ __forceinline__ float bflo(unsigned p) { return __uint_as_float(p << 16); }
__device__ __forceinline__ float bfhi(unsigned p) { return __uint_as_float(p & 0xffff0000u); }

// packed edge: bits 0..16 = src (N<2^17); bits 17..31 = 15-bit weight
// (8 exp + 7 mant, sign implicit negative).
__device__ __forceinline__ int esrc(unsigned v) { return (int)(v & 0x1FFFFu); }
__device__ __forceinline__ float ew(unsigned v) {
    return __uint_as_float(0x80000000u | ((v >> 17) << 16));
}

// ---------------- preprocessing: atomic-free two-level counting sort ----------

__global__ __launch_bounds__(256) void part_count_kernel(
    const int* __restrict__ ei, int* __restrict__ cntD, int* __restrict__ cntS) {
    __shared__ int hd[NBK], hs[NBK];
    int tid = threadIdx.x;
    for (int i = tid; i < NBK; i += 256) { hd[i] = 0; hs[i] = 0; }
    __syncthreads();
    int e0 = blockIdx.x * CHUNK;
    for (int e = e0 + tid; e < e0 + CHUNK; e += 256) {
        int s = ei[e], d = ei[N_EDGES + e];
        atomicAdd(&hs[s >> 8], 1);
        atomicAdd(&hd[d >> 8], 1);
    }
    __syncthreads();
    for (int i = tid; i < NBK; i += 256) {
        cntD[i * NBLK + blockIdx.x] = hd[i];
        cntS[i * NBLK + blockIdx.x] = hs[i];
    }
}

__global__ __launch_bounds__(256) void scanA_kernel(const int* __restrict__ in,
                                                    int* __restrict__ out,
                                                    int* __restrict__ bsum, int L) {
    __shared__ int sm[256];
    int i = blockIdx.x * 256 + threadIdx.x;
    int v = (i < L) ? in[i] : 0;
    sm[threadIdx.x] = v;
    __syncthreads();
    for (int off = 1; off < 256; off <<= 1) {
        int t = (threadIdx.x >= off) ? sm[threadIdx.x - off] : 0;
        __syncthreads();
        sm[threadIdx.x] += t;
        __syncthreads();
    }
    if (i < L) out[i] = sm[threadIdx.x] - v;
    if (threadIdx.x == 255) bsum[blockIdx.x] = sm[255];
}

__global__ __launch_bounds__(1024) void scanB_kernel(int* __restrict__ bsum, int nb) {
    __shared__ int sm[1024];
    int t = threadIdx.x;
    int v = (t < nb) ? bsum[t] : 0;
    sm[t] = v;
    __syncthreads();
    for (int off = 1; off < 1024; off <<= 1) {
        int u = (t >= off) ? sm[t - off] : 0;
        __syncthreads();
        sm[t] += u;
        __syncthreads();
    }
    if (t < nb) bsum[t] = sm[t] - v;
}

__global__ __launch_bounds__(256) void scanC_kernel(int* __restrict__ out,
                                                    const int* __restrict__ bsum, int L) {
    int i = blockIdx.x * 256 + threadIdx.x;
    if (i < L) out[i] += bsum[blockIdx.x];
}

__global__ __launch_bounds__(256) void part_scatter_kernel(
    const int* __restrict__ ei, const int* __restrict__ scanD,
    const int* __restrict__ scanS, int2* __restrict__ edgepart,
    int* __restrict__ srcpart) {
    __shared__ int curD[NBK], curS[NBK];
    int tid = threadIdx.x;
    for (int i = tid; i < NBK; i += 256) {
        curD[i] = scanD[i * NBLK + blockIdx.x];
        curS[i] = scanS[i * NBLK + blockIdx.x];
    }
    __syncthreads();
    int e0 = blockIdx.x * CHUNK;
    for (int e = e0 + tid; e < e0 + CHUNK; e += 256) {
        int s = ei[e], d = ei[N_EDGES + e];
        int pd = atomicAdd(&curD[d >> 8], 1);
        edgepart[pd] = make_int2(s, d);
        int ps = atomicAdd(&curS[s >> 8], 1);
        srcpart[ps] = s;
    }
}

__global__ __launch_bounds__(256) void deg_kernel(const int* __restrict__ srcpart,
                                                  const int* __restrict__ scanS,
                                                  float* __restrict__ dis) {
    __shared__ int cnt[256];
    int b = blockIdx.x, tid = threadIdx.x;
    cnt[tid] = 0;
    __syncthreads();
    int beg = scanS[b * NBLK];
    int end = (b + 1 < NBK) ? scanS[(b + 1) * NBLK] : N_EDGES;
    for (int j = beg + tid; j < end; j += 256)
        atomicAdd(&cnt[srcpart[j] & 255], 1);
    __syncthreads();
    int node = b * 256 + tid;
    if (node < N_NODES) dis[node] = cnt[tid] > 0 ? rsqrtf((float)cnt[tid]) : 0.f;
}

__global__ __launch_bounds__(256) void csr_kernel(const int2* __restrict__ edgepart,
                                                  const int* __restrict__ scanD,
                                                  const float* __restrict__ dis,
                                                  int* __restrict__ rp,
                                                  unsigned* __restrict__ csrc) {
    __shared__ int cnt[256];
    __shared__ int lofs[256];
    __shared__ float disl[256];
    int b = blockIdx.x, tid = threadIdx.x;
    int beg = scanD[b * NBLK];
    int end = (b + 1 < NBK) ? scanD[(b + 1) * NBLK] : N_EDGES;
    int node = b * 256 + tid;
    cnt[tid] = 0;
    disl[tid] = (node < N_NODES) ? dis[node] : 0.f;
    __syncthreads();
    for (int j = beg + tid; j < end; j += 256)
        atomicAdd(&cnt[edgepart[j].y & 255], 1);
    __syncthreads();
    int v = cnt[tid];
    lofs[tid] = v;
    __syncthreads();
    for (int off = 1; off < 256; off <<= 1) {
        int t = (tid >= off) ? lofs[tid - off] : 0;
        __syncthreads();
        lofs[tid] += t;
        __syncthreads();
    }
    int myexc = lofs[tid] - v;
    if (node < N_NODES) rp[node] = beg + myexc;
    if (b == NBK - 1 && tid == 0) rp[N_NODES] = N_EDGES;
    __syncthreads();
    lofs[tid] = myexc;
    cnt[tid] = 0;
    __syncthreads();
    for (int j = beg + tid; j < end; j += 256) {
        int2 e = edgepart[j];
        int dl = e.y & 255;
        int pos = beg + lofs[dl] + atomicAdd(&cnt[dl], 1);
        unsigned u = __float_as_uint(-(dis[e.x] * disl[dl]));
        u += 0x7fffu + ((u >> 16) & 1u);
        unsigned wb = (u >> 16) & 0x7FFFu;
        csrc[pos] = (unsigned)e.x | (wb << 17);
    }
}

// pack x [N,64] f32 -> bf16 (row = 16 uint2 = 128B)
__global__ void pack_x_kernel(const float* __restrict__ x, uint2* __restrict__ xbf) {
    int i = blockIdx.x * blockDim.x + threadIdx.x;     // over N*16
    if (i >= N_NODES * 16) return;
    float4 v = ((const float4*)x)[i];
    xbf[i] = make_uint2(bf16pack(v.x, v.y), bf16pack(v.z, v.w));
}

// ---------------- fused Clenshaw step ----------------
// OUT[row] = SCALE * sum_j w_j*INb[src_j] + A'[row]@W - (HAS_B2 ? B2b[row] : 0)
// All accesses NORMAL cached (R12 lesson: nt on re-read/re-gathered data forces
// HBM re-fetch; L3 is 256MB and holds everything).

template <int FI, int SCALE, bool HAS_B2, bool BN_A, bool FUSE_STATS>
__global__ __launch_bounds__(256) void cheb_step_kernel(
    const int* __restrict__ rp, const unsigned* __restrict__ csrc,
    const uint2* __restrict__ INb, const uint2* __restrict__ B2b,
    const uint2* __restrict__ Ab, const float* __restrict__ W,
    const float* __restrict__ ss, unsigned long long* __restrict__ OUT,
    float* __restrict__ partials) {
    constexpr int RU2 = FI / 4;                  // uint2 per A row
    __shared__ float Wl[FI * 36];
    __shared__ float Atile[28][FI + 1];
    __shared__ float ls[72];
    int tid = threadIdx.x;                       // 252 threads = 28 rows x 9 lanes
    for (int i = tid; i < FI * 36; i += 252) Wl[i] = W[i];
    int r0 = blockIdx.x * 28;
    const long long* ab8 = (const long long*)Ab;
    for (int i = tid; i < 28 * RU2; i += 252) {
        int r = i / RU2, u = i % RU2;
        int row = r0 + r;
        long long av = (row < N_NODES) ? ab8[(size_t)row * RU2 + u] : 0LL;
        unsigned lo = (unsigned)av, hi = (unsigned)(av >> 32);
        float f0 = bflo(lo), f1 = bfhi(lo), f2 = bflo(hi), f3 = bfhi(hi);
        if (BN_A) {
            int f = u * 4;
            f0 = fmaxf(fmaf(ss[f + 0], f0, ss[36 + f + 0]), 0.f);
            f1 = fmaxf(fmaf(ss[f + 1], f1, ss[36 + f + 1]), 0.f);
            f2 = fmaxf(fmaf(ss[f + 2], f2, ss[36 + f + 2]), 0.f);
            f3 = fmaxf(fmaf(ss[f + 3], f3, ss[36 + f + 3]), 0.f);
        }
        Atile[r][u * 4 + 0] = f0; Atile[r][u * 4 + 1] = f1;
        Atile[r][u * 4 + 2] = f2; Atile[r][u * 4 + 3] = f3;
    }
    if (FUSE_STATS && tid < 72) ls[tid] = 0.f;
    __syncthreads();
    int r = tid / 9, c = tid % 9;
    int row = r0 + r;
    bool valid = row < N_NODES;
    float ax = 0, ay = 0, az = 0, aw = 0;
    float bx = 0, by = 0, bz = 0, bw = 0;
    float cx = 0, cy = 0, cz = 0, cw = 0;
    float dx = 0, dy = 0, dz = 0, dw = 0;
    if (SCALE != 0 && valid) {
        int beg = rp[row], end = rp[row + 1];
        int j = beg;
        for (; j + 7 < end; j += 8) {
            unsigned v0 = csrc[j],     v1 = csrc[j + 1], v2 = csrc[j + 2], v3 = csrc[j + 3];
            unsigned v4 = csrc[j + 4], v5 = csrc[j + 5], v6 = csrc[j + 6], v7 = csrc[j + 7];
            uint2 u0 = INb[(size_t)esrc(v0) * 9 + c];
            uint2 u1 = INb[(size_t)esrc(v1) * 9 + c];
            uint2 u2 = INb[(size_t)esrc(v2) * 9 + c];
            uint2 u3 = INb[(size_t)esrc(v3) * 9 + c];
            uint2 u4 = INb[(size_t)esrc(v4) * 9 + c];
            uint2 u5 = INb[(size_t)esrc(v5) * 9 + c];
            uint2 u6 = INb[(size_t)esrc(v6) * 9 + c];
            uint2 u7 = INb[(size_t)esrc(v7) * 9 + c];
            float w0 = ew(v0), w1 = ew(v1), w2 = ew(v2), w3 = ew(v3);
            float w4 = ew(v4), w5 = ew(v5), w6 = ew(v6), w7 = ew(v7);
            ax = fmaf(w0, bflo(u0.x), ax); ay = fmaf(w0, bfhi(u0.x), ay);
            az = fmaf(w0, bflo(u0.y), az); aw = fmaf(w0, bfhi(u0.y), aw);
            bx = fmaf(w1, bflo(u1.x), bx); by = fmaf(w1, bfhi(u1.x), by);
            bz = fmaf(w1, bflo(u1.y), bz); bw = fmaf(w1, bfhi(u1.y), bw);
            cx = fmaf(w2, bflo(u2.x), cx); cy = fmaf(w2, bfhi(u2.x), cy);
            cz = fmaf(w2, bflo(u2.y), cz); cw = fmaf(w2, bfhi(u2.y), cw);
            dx = fmaf(w3, bflo(u3.x), dx); dy = fmaf(w3, bfhi(u3.x), dy);
            dz = fmaf(w3, bflo(u3.y), dz); dw = fmaf(w3, bfhi(u3.y), dw);
            ax = fmaf(w4, bflo(u4.x), ax); ay = fmaf(w4, bfhi(u4.x), ay);
            az = fmaf(w4, bflo(u4.y), az); aw = fmaf(w4, bfhi(u4.y), aw);
            bx = fmaf(w5, bflo(u5.x), bx); by = fmaf(w5, bfhi(u5.x), by);
            bz = fmaf(w5, bflo(u5.y), bz); bw = fmaf(w5, bfhi(u5.y), bw);
            cx = fmaf(w6, bflo(u6.x), cx); cy = fmaf(w6, bfhi(u6.x), cy);
            cz = fmaf(w6, bflo(u6.y), cz); cw = fmaf(w6, bfhi(u6.y), cw);
            dx = fmaf(w7, bflo(u7.x), dx); dy = fmaf(w7, bfhi(u7.x), dy);
            dz = fmaf(w7, bflo(u7.y), dz); dw = fmaf(w7, bfhi(u7.y), dw);
        }
        for (; j < end; ++j) {
            unsigned v = csrc[j];
            uint2 u = INb[(size_t)esrc(v) * 9 + c];
            float w = ew(v);
            ax = fmaf(w, bflo(u.x), ax); ay = fmaf(w, bfhi(u.x), ay);
            az = fmaf(w, bflo(u.y), az); aw = fmaf(w, bfhi(u.y), aw);
        }
        ax += bx + cx + dx; ay += by + cy + dy;
        az += bz + cz + dz; aw += bw + cw + dw;
    }
    float px = 0, py = 0, pz = 0, pw = 0;
    const float4* Wl4 = (const float4*)Wl;
#pragma unroll 4
    for (int f = 0; f < FI; ++f) {
        float a = Atile[r][f];
        float4 wv = Wl4[f * 9 + c];
        px = fmaf(a, wv.x, px); py = fmaf(a, wv.y, py);
        pz = fmaf(a, wv.z, pz); pw = fmaf(a, wv.w, pw);
    }
    const float S = (float)SCALE;
    float4 o;
    o.x = fmaf(S, ax, px); o.y = fmaf(S, ay, py);
    o.z = fmaf(S, az, pz); o.w = fmaf(S, aw, pw);
    if (valid) {
        if (HAS_B2) {
            uint2 u = B2b[(size_t)row * 9 + c];
            o.x -= bflo(u.x); o.y -= bfhi(u.x);
            o.z -= bflo(u.y); o.w -= bfhi(u.y);
        }
        unsigned long long pv = (unsigned long long)bf16pack(o.x, o.y)
                              | ((unsigned long long)bf16pack(o.z, o.w) << 32);
        OUT[(size_t)row * 9 + c] = pv;
        if (FUSE_STATS) {
            atomicAdd(&ls[c * 4 + 0], o.x); atomicAdd(&ls[36 + c * 4 + 0], o.x * o.x);
            atomicAdd(&ls[c * 4 + 1], o.y); atomicAdd(&ls[36 + c * 4 + 1], o.y * o.y);
            atomicAdd(&ls[c * 4 + 2], o.z); atomicAdd(&ls[36 + c * 4 + 2], o.z * o.z);
            atomicAdd(&ls[c * 4 + 3], o.w); atomicAdd(&ls[36 + c * 4 + 3], o.w * o.w);
        }
    }
    if (FUSE_STATS) {
        __syncthreads();
        if (tid < 72) partials[blockIdx.x * 72 + tid] = ls[tid];
    }
}

// ---------------- GIN gather (projection-first), bf16 out + stats ----------------

__global__ __launch_bounds__(256) void gin_gather_kernel(
    const int* __restrict__ rp, const unsigned* __restrict__ csrc,
    const uint2* __restrict__ Yb, const float* __restrict__ b1,
    const float* __restrict__ w2, const float* __restrict__ b2,
    unsigned long long* __restrict__ OUT, float* __restrict__ partials) {
    __shared__ float W2l[36 * 36];
    __shared__ float B1l[36], B2l[36];
    __shared__ float M1t[28][37];
    __shared__ float ls[72];
    int tid = threadIdx.x;                       // 252 = 28 rows x 9 lanes
    for (int i = tid; i < 36 * 36; i += 252) W2l[i] = w2[i];
    if (tid < 36) { B1l[tid] = b1[tid]; B2l[tid] = b2[tid]; }
    if (tid < 72) ls[tid] = 0.f;
    __syncthreads();
    int r = tid / 9, c = tid % 9;
    int row = blockIdx.x * 28 + r;
    bool valid = row < N_NODES;
    float ax = 0, ay = 0, az = 0, aw = 0;
    float bx = 0, by = 0, bz = 0, bw = 0;
    float cx = 0, cy = 0, cz = 0, cw = 0;
    float dx = 0, dy = 0, dz = 0, dw = 0;
    if (valid) {
        uint2 us = Yb[(size_t)row * 9 + c];
        ax = bflo(us.x); ay = bfhi(us.x); az = bflo(us.y); aw = bfhi(us.y);
        int beg = rp[row], end = rp[row + 1];
        int j = beg;
        for (; j + 7 < end; j += 8) {
            int s0 = esrc(csrc[j]),     s1 = esrc(csrc[j + 1]);
            int s2 = esrc(csrc[j + 2]), s3 = esrc(csrc[j + 3]);
            int s4 = esrc(csrc[j + 4]), s5 = esrc(csrc[j + 5]);
            int s6 = esrc(csrc[j + 6]), s7 = esrc(csrc[j + 7]);
            uint2 u0 = Yb[(size_t)s0 * 9 + c];
            uint2 u1 = Yb[(size_t)s1 * 9 + c];
            uint2 u2 = Yb[(size_t)s2 * 9 + c];
            uint2 u3 = Yb[(size_t)s3 * 9 + c];
            uint2 u4 = Yb[(size_t)s4 * 9 + c];
            uint2 u5 = Yb[(size_t)s5 * 9 + c];
            uint2 u6 = Yb[(size_t)s6 * 9 + c];
            uint2 u7 = Yb[(size_t)s7 * 9 + c];
            ax += bflo(u0.x) + bflo(u4.x); ay += bfhi(u0.x) + bfhi(u4.x);
            az += bflo(u0.y) + bflo(u4.y); aw += bfhi(u0.y) + bfhi(u4.y);
            bx += bflo(u1.x) + bflo(u5.x); by += bfhi(u1.x) + bfhi(u5.x);
            bz += bflo(u1.y) + bflo(u5.y); bw += bfhi(u1.y) + bfhi(u5.y);
            cx += bflo(u2.x) + bflo(u6.x); cy += bfhi(u2.x) + bfhi(u6.x);
            cz += bflo(u2.y) + bflo(u6.y); cw += bfhi(u2.y) + bfhi(u6.y);
            dx += bflo(u3.x) + bflo(u7.x); dy += bfhi(u3.x) + bfhi(u7.x);
            dz += bflo(u3.y) + bflo(u7.y); dw += bfhi(u3.y) + bfhi(u7.y);
        }
        for (; j < end; ++j) {
            uint2 u = Yb[(size_t)esrc(csrc[j]) * 9 + c];
            ax += bflo(u.x); ay += bfhi(u.x);
            az += bflo(u.y); aw += bfhi(u.y);
        }
        ax += bx + cx + dx; ay += by + cy + dy;
        az += bz + cz + dz; aw += bw + cw + dw;
    }
    float m0 = fmaxf(ax + B1l[c * 4 + 0], 0.f);
    float m1 = fmaxf(ay + B1l[c * 4 + 1], 0.f);
    float m2 = fmaxf(az + B1l[c * 4 + 2], 0.f);
    float m3 = fmaxf(aw + B1l[c * 4 + 3], 0.f);
    M1t[r][c * 4 + 0] = m0; M1t[r][c * 4 + 1] = m1;
    M1t[r][c * 4 + 2] = m2; M1t[r][c * 4 + 3] = m3;
    __syncthreads();
    float o0 = B2l[c * 4 + 0], o1 = B2l[c * 4 + 1];
    float o2 = B2l[c * 4 + 2], o3 = B2l[c * 4 + 3];
    const float4* W2l4 = (const float4*)W2l;
#pragma unroll 4
    for (int f = 0; f < 36; ++f) {
        float a = M1t[r][f];
        float4 wv = W2l4[f * 9 + c];
        o0 = fmaf(a, wv.x, o0); o1 = fmaf(a, wv.y, o1);
        o2 = fmaf(a, wv.z, o2); o3 = fmaf(a, wv.w, o3);
    }
    o0 = fmaxf(o0, 0.f); o1 = fmaxf(o1, 0.f);
    o2 = fmaxf(o2, 0.f); o3 = fmaxf(o3, 0.f);
    if (valid) {
        unsigned long long pv = (unsigned long long)bf16pack(o0, o1)
                              | ((unsigned long long)bf16pack(o2, o3) << 32);
        OUT[(size_t)row * 9 + c] = pv;
        atomicAdd(&ls[c * 4 + 0], o0); atomicAdd(&ls[36 + c * 4 + 0], o0 * o0);
        atomicAdd(&ls[c * 4 + 1], o1); atomicAdd(&ls[36 + c * 4 + 1], o1 * o1);
        atomicAdd(&ls[c * 4 + 2], o2); atomicAdd(&ls[36 + c * 4 + 2], o2 * o2);
        atomicAdd(&ls[c * 4 + 3], o3); atomicAdd(&ls[36 + c * 4 + 3], o3 * o3);
    }
    __syncthreads();
    if (tid < 72) partials[blockIdx.x * 72 + tid] = ls[tid];
}

// ---------------- finalize: reduce partials -> BN scale/shift ----------------

__global__ __launch_bounds__(256) void finalize_kernel(
    const float* __restrict__ partials, int nb, const float* __restrict__ g,
    const float* __restrict__ be, float* __restrict__ ss) {
    __shared__ float rs[256], rq[256];
    int c = blockIdx.x;
    int t = threadIdx.x;
    float s = 0.f, q = 0.f;
    for (int i = t; i < nb; i += 256) {
        s += partials[i * 72 + c];
        q += partials[i * 72 + c + 36];
    }
    rs[t] = s; rq[t] = q;
    __syncthreads();
    for (int off = 128; off > 0; off >>= 1) {
        if (t < off) { rs[t] += rs[t + off]; rq[t] += rq[t + off]; }
        __syncthreads();
    }
    if (t == 0) {
        float m = rs[0] / (float)N_NODES;
        float v = rq[0] / (float)N_NODES - m * m;
        float sc = g[c] * rsqrtf(v + 1e-5f);
        ss[c] = sc;
        ss[36 + c] = be[c] - m * sc;
    }
}

// ---------------- final concat GEMM, bf16 72B-row inputs (32 rows/block) -------

__global__ __launch_bounds__(256) void fused3_kernel(
    const uint2* __restrict__ X1b, const float* __restrict__ ssA,
    const uint2* __restrict__ X2b, const float* __restrict__ ssB,
    const uint2* __restrict__ X3b, const float* __restrict__ ssC,
    const float* __restrict__ W, const float* __restrict__ b,
    float* __restrict__ out) {
    __shared__ float Wl[108 * 32];       // 13.8 KB
    __shared__ float Al[32][109];        // 13.9 KB
    int tid = threadIdx.x;
    for (int i = tid; i < 108 * 32; i += 256) Wl[i] = W[i];
    int r0 = blockIdx.x * 32;
    for (int i = tid; i < 32 * 108; i += 256) {
        int r = i / 108, f = i % 108;
        int row = r0 + r;
        float v = 0.f;
        if (row < N_NODES) {
            int t = f / 36, ff = f % 36;
            const unsigned short* base =
                (const unsigned short*)(t == 0 ? X1b : (t == 1 ? X2b : X3b));
            float xv = __uint_as_float((unsigned)base[(size_t)row * 36 + ff] << 16);
            if (t == 0)      v = fmaxf(fmaf(ssA[ff], xv, ssA[36 + ff]), 0.f);
            else if (t == 1) v = fmaxf(fmaf(ssB[ff], xv, ssB[36 + ff]), 0.f);
            else             v = fmaf(ssC[ff], xv, ssC[36 + ff]);
        }
        Al[r][f] = v;
    }
    __syncthreads();
    int r = tid >> 3, q = tid & 7;       // 32 rows x 8 threads, 4 cols each
    int row = r0 + r;
    if (row >= N_NODES) return;
    float acc[4];
#pragma unroll
    for (int j = 0; j < 4; ++j) acc[j] = b[q * 4 + j];
    for (int f = 0; f < 108; ++f) {
        float a = Al[r][f];
#pragma unroll
        for (int j = 0; j < 4; ++j)
            acc[j] = fmaf(a, Wl[f * 32 + q * 4 + j], acc[j]);
    }
#pragma unroll
    for (int j = 0; j < 4; ++j) out[(size_t)row * 32 + q * 4 + j] = acc[j];
}

// ---------------- launch ----------------

extern "C" void kernel_launch(void* const* d_in, const int* in_sizes, int n_in,
                              void* d_out, int out_size, void* d_ws, size_t ws_size,
                              hipStream_t stream) {
    const float* x      = (const float*)d_in[0];
    const int*   ei     = (const int*)d_in[1];
    const float* W1_1   = (const float*)d_in[2];
    // b1_1 / b1_2 cancel exactly under training-mode BN -> dropped.
    const float* g1_1   = (const float*)d_in[4];
    const float* be1_1  = (const float*)d_in[5];
    const float* W1_2   = (const float*)d_in[6];
    const float* g1_2   = (const float*)d_in[8];
    const float* be1_2  = (const float*)d_in[9];
    const float* gin_w1 = (const float*)d_in[10];
    const float* gin_b1 = (const float*)d_in[11];
    const float* gin_w2 = (const float*)d_in[12];
    const float* gin_b2 = (const float*)d_in[13];
    const float* g2     = (const float*)d_in[14];
    const float* be2    = (const float*)d_in[15];
    const float* W4     = (const float*)d_in[16];
    const float* b4     = (const float*)d_in[17];
    float* out = (float*)d_out;

    char* ws = (char*)d_ws;
    size_t off = 0;
    auto alloc = [&](size_t bytes) -> char* {
        char* p = ws + off;
        off = (off + bytes + 255) & ~(size_t)255;
        return p;
    };
    int*   cntD  = (int*)alloc((size_t)LCNT * 4);
    int*   cntS  = (int*)alloc((size_t)LCNT * 4);
    int*   bsum  = (int*)alloc(1024 * 4);
    int*   rp    = (int*)alloc((size_t)(N_NODES + 1) * 4);
    float* dis   = (float*)alloc((size_t)N_NODES * 4);
    int2*  edgepart = (int2*)alloc((size_t)N_EDGES * 8);
    int*   srcpart  = (int*)alloc((size_t)N_EDGES * 4);
    unsigned* csrc = (unsigned*)alloc((size_t)N_EDGES * 4);
    float* ssA   = (float*)alloc(72 * 4);
    float* ssB   = (float*)alloc(72 * 4);
    float* ssC   = (float*)alloc(72 * 4);
    float* partials = (float*)alloc((size_t)6250 * 72 * 4);
    constexpr size_t NBBF = (size_t)N_NODES * 72;          // bf16 packed 72B rows
    uint2* xbf = (uint2*)alloc((size_t)N_NODES * 128);     // bf16 [N,64] 128B rows
    uint2* R0  = (uint2*)alloc(NBBF);
    uint2* R1  = (uint2*)alloc(NBBF);
    uint2* R2  = (uint2*)alloc(NBBF);
    uint2* X1b = (uint2*)alloc(NBBF);
    uint2* X2b = (uint2*)alloc(NBBF);
    uint2* X3b = (uint2*)alloc(NBBF);
    if (off > ws_size) return;

    // ---- preprocessing: counting-sort CSR build (no global atomics) ----
    part_count_kernel<<<NBLK, 256, 0, stream>>>(ei, cntD, cntS);
    scanA_kernel<<<SCAN_BLKS, 256, 0, stream>>>(cntD, cntD, bsum, LCNT);
    scanB_kernel<<<1, 1024, 0, stream>>>(bsum, SCAN_BLKS);
    scanC_kernel<<<SCAN_BLKS, 256, 0, stream>>>(cntD, bsum, LCNT);
    scanA_kernel<<<SCAN_BLKS, 256, 0, stream>>>(cntS, cntS, bsum, LCNT);
    scanB_kernel<<<1, 1024, 0, stream>>>(bsum, SCAN_BLKS);
    scanC_kernel<<<SCAN_BLKS, 256, 0, stream>>>(cntS, bsum, LCNT);
    part_scatter_kernel<<<NBLK, 256, 0, stream>>>(ei, cntD, cntS, edgepart, srcpart);
    deg_kernel<<<NBK, 256, 0, stream>>>(srcpart, cntS, dis);
    csr_kernel<<<NBK, 256, 0, stream>>>(edgepart, cntD, dis, rp, csrc);
    pack_x_kernel<<<(N_NODES * 16 + 255) / 256, 256, 0, stream>>>(x, xbf);

    const int STEP_BLKS = (N_NODES + 27) / 28;        // 3572
    const int F3_BLKS   = (N_NODES + 31) / 32;        // 3125

    auto U64 = [](uint2* p) { return (unsigned long long*)p; };

    // ---- conv1_1 (Clenshaw, FI=64, A=xbf) ----
    cheb_step_kernel<64, 0, false, false, false><<<STEP_BLKS, 252, 0, stream>>>(
        rp, csrc, nullptr, nullptr, xbf, W1_1 + 7 * 2304, nullptr, U64(R0), nullptr);
    cheb_step_kernel<64, 2, false, false, false><<<STEP_BLKS, 252, 0, stream>>>(
        rp, csrc, R0, nullptr, xbf, W1_1 + 6 * 2304, nullptr, U64(R1), nullptr);
    cheb_step_kernel<64, 2, true, false, false><<<STEP_BLKS, 252, 0, stream>>>(
        rp, csrc, R1, R0, xbf, W1_1 + 5 * 2304, nullptr, U64(R2), nullptr);
    cheb_step_kernel<64, 2, true, false, false><<<STEP_BLKS, 252, 0, stream>>>(
        rp, csrc, R2, R1, xbf, W1_1 + 4 * 2304, nullptr, U64(R0), nullptr);
    cheb_step_kernel<64, 2, true, false, false><<<STEP_BLKS, 252, 0, stream>>>(
        rp, csrc, R0, R2, xbf, W1_1 + 3 * 2304, nullptr, U64(R1), nullptr);
    cheb_step_kernel<64, 2, true, false, false><<<STEP_BLKS, 252, 0, stream>>>(
        rp, csrc, R1, R0, xbf, W1_1 + 2 * 2304, nullptr, U64(R2), nullptr);
    cheb_step_kernel<64, 2, true, false, false><<<STEP_BLKS, 252, 0, stream>>>(
        rp, csrc, R2, R1, xbf, W1_1 + 1 * 2304, nullptr, U64(R0), nullptr);
    cheb_step_kernel<64, 1, true, false, true><<<STEP_BLKS, 252, 0, stream>>>(
        rp, csrc, R0, R2, xbf, W1_1 + 0 * 2304, nullptr, U64(X1b), partials);
    finalize_kernel<<<36, 256, 0, stream>>>(partials, STEP_BLKS, g1_1, be1_1, ssA);

    // ---- conv1_2 (Clenshaw, FI=36, A=X1b with BN ssA) ----
    cheb_step_kernel<36, 0, false, true, false><<<STEP_BLKS, 252, 0, stream>>>(
        rp, csrc, nullptr, nullptr, X1b, W1_2 + 7 * 1296, ssA, U64(R0), nullptr);
    cheb_step_kernel<36, 2, false, true, false><<<STEP_BLKS, 252, 0, stream>>>(
        rp, csrc, R0, nullptr, X1b, W1_2 + 6 * 1296, ssA, U64(R1), nullptr);
    cheb_step_kernel<36, 2, true, true, false><<<STEP_BLKS, 252, 0, stream>>>(
        rp, csrc, R1, R0, X1b, W1_2 + 5 * 1296, ssA, U64(R2), nullptr);
    cheb_step_kernel<36, 2, true, true, false><<<STEP_BLKS, 252, 0, stream>>>(
        rp, csrc, R2, R1, X1b, W1_2 + 4 * 1296, ssA, U64(R0), nullptr);
    cheb_step_kernel<36, 2, true, true, false><<<STEP_BLKS, 252, 0, stream>>>(
        rp, csrc, R0, R2, X1b, W1_2 + 3 * 1296, ssA, U64(R1), nullptr);
    cheb_step_kernel<36, 2, true, true, false><<<STEP_BLKS, 252, 0, stream>>>(
        rp, csrc, R1, R0, X1b, W1_2 + 2 * 1296, ssA, U64(R2), nullptr);
    cheb_step_kernel<36, 2, true, true, false><<<STEP_BLKS, 252, 0, stream>>>(
        rp, csrc, R2, R1, X1b, W1_2 + 1 * 1296, ssA, U64(R0), nullptr);
    cheb_step_kernel<36, 1, true, true, true><<<STEP_BLKS, 252, 0, stream>>>(
        rp, csrc, R0, R2, X1b, W1_2 + 0 * 1296, ssA, U64(X2b), partials);
    finalize_kernel<<<36, 256, 0, stream>>>(partials, STEP_BLKS, g1_2, be1_2, ssB);

    // ---- GIN (projection-first: y = x@gin_w1 from xbf, then 36-wide gather) ----
    cheb_step_kernel<64, 0, false, false, false><<<STEP_BLKS, 252, 0, stream>>>(
        rp, csrc, nullptr, nullptr, xbf, gin_w1, nullptr, U64(R0), nullptr);
    gin_gather_kernel<<<STEP_BLKS, 252, 0, stream>>>(rp, csrc, R0, gin_b1,
                                                     gin_w2, gin_b2, U64(X3b), partials);
    finalize_kernel<<<36, 256, 0, stream>>>(partials, STEP_BLKS, g2, be2, ssC);

    // ---- final concat GEMM ----
    fused3_kernel<<<F3_BLKS, 256, 0, stream>>>(X1b, ssA, X2b, ssB, X3b, ssC, W4, b4, out);
}